// Round 1
// baseline (1674.335 us; speedup 1.0000x reference)
//
#include <hip/hip_runtime.h>
#include <cstdint>

#define S_LEN 4096
#define D_MODEL 768
#define NHEAD 12
#define DHE 64
#define DFF_ 3072
#define NL 4
#define W1_ 128
#define NC_ 32

typedef __attribute__((ext_vector_type(8))) short v8s;
typedef __attribute__((ext_vector_type(4))) float v4f;

__device__ __forceinline__ short f2bf(float f) {
  union { float f; unsigned u; } x; x.f = f;
  unsigned r = x.u + 0x7fffu + ((x.u >> 16) & 1u);
  return (short)(r >> 16);
}

__device__ __forceinline__ void load_lds16(const short* g, short* l) {
  __builtin_amdgcn_global_load_lds((const __attribute__((address_space(1))) void*)g,
                                   (__attribute__((address_space(3))) void*)l, 16, 0, 0);
}

// ---------------- weight transpose f32[K,N] -> bf16[N,K], per-layer via blockIdx.z
__global__ __launch_bounds__(256)
void transpose_w(const float* __restrict__ in, short* __restrict__ out, int K, int N)
{
  __shared__ float t[32][33];
  const int n0 = blockIdx.x * 32, k0 = blockIdx.y * 32;
  const float* src = in + (size_t)blockIdx.z * K * N;
  short* dst = out + (size_t)blockIdx.z * K * N;
  const int tx = threadIdx.x, ty = threadIdx.y;   // (32,8)
#pragma unroll
  for (int i = 0; i < 4; ++i)
    t[ty + 8*i][tx] = src[(size_t)(k0 + ty + 8*i) * N + n0 + tx];
  __syncthreads();
#pragma unroll
  for (int i = 0; i < 4; ++i)
    dst[(size_t)(n0 + ty + 8*i) * K + k0 + tx] = f2bf(t[tx][ty + 8*i]);
}

// ---------------- V transpose bf16 [B,S,H,DH] -> [B,H,DH,S]
__global__ __launch_bounds__(512)
void vtrans(const short* __restrict__ v, short* __restrict__ vt)
{
  __shared__ short t[64][65];
  const int s0 = blockIdx.x * 64, h = blockIdx.y, b = blockIdx.z;
  const int tx = threadIdx.x, ty = threadIdx.y;   // (64,8)
#pragma unroll
  for (int i = 0; i < 8; ++i)
    t[ty + 8*i][tx] = v[((size_t)(b * S_LEN + s0 + ty + 8*i) * NHEAD + h) * DHE + tx];
  __syncthreads();
#pragma unroll
  for (int i = 0; i < 8; ++i)
    vt[((size_t)(b * NHEAD + h) * DHE + ty + 8*i) * S_LEN + s0 + tx] = t[tx][ty + 8*i];
}

// ---------------- LayerNorm. MODE 0: embed (in0 + pos + tok), MODE 1: residual (in0 + in1)
template<int MODE>
__global__ __launch_bounds__(256)
void ln_kernel(const float* __restrict__ in0, const float* __restrict__ in1,
               const float* __restrict__ in2,
               const float* __restrict__ gamma, const float* __restrict__ beta,
               float* __restrict__ outf, short* __restrict__ outb)
{
  __shared__ float red[8];
  const int row = blockIdx.x;
  const int tid = threadIdx.x;
  const int wave = tid >> 6, lane = tid & 63;
  float v[3];
#pragma unroll
  for (int i = 0; i < 3; ++i) {
    const int c = tid + i * 256;
    const size_t idx = (size_t)row * D_MODEL + c;
    if (MODE == 0) {
      const int s = row & (S_LEN - 1);
      v[i] = in0[idx] + in1[(size_t)(2 + s) * D_MODEL + c] + in2[c];
    } else {
      v[i] = in0[idx] + in1[idx];
    }
  }
  float sum = v[0] + v[1] + v[2];
#pragma unroll
  for (int m = 1; m < 64; m <<= 1) sum += __shfl_xor(sum, m, 64);
  if (lane == 0) red[wave] = sum;
  __syncthreads();
  const float mean = (red[0] + red[1] + red[2] + red[3]) * (1.0f / 768.0f);
  float sq = 0.f;
#pragma unroll
  for (int i = 0; i < 3; ++i) { float d = v[i] - mean; sq += d * d; }
#pragma unroll
  for (int m = 1; m < 64; m <<= 1) sq += __shfl_xor(sq, m, 64);
  if (lane == 0) red[4 + wave] = sq;
  __syncthreads();
  const float var = (red[4] + red[5] + red[6] + red[7]) * (1.0f / 768.0f);
  const float rstd = 1.0f / sqrtf(var + 1e-12f);
#pragma unroll
  for (int i = 0; i < 3; ++i) {
    const int c = tid + i * 256;
    const size_t idx = (size_t)row * D_MODEL + c;
    const float o = (v[i] - mean) * rstd * gamma[c] + beta[c];
    outf[idx] = o;
    outb[idx] = f2bf(o);
  }
}

// ---------------- GEMM: C[M,N] = A[M,K](bf16) @ Bt[N,K]^T(bf16) + bias
// EPI 0: bf16 out, (acc+bias)*scale.  EPI 1: f32 out, acc+bias.  EPI 2: gelu -> bf16
template<int EPI>
__global__ __launch_bounds__(256)
void gemm_bt(const short* __restrict__ A, const short* __restrict__ Bt,
             const float* __restrict__ bias, void* __restrict__ outp,
             int M, int N, int K, float scale)
{
  __shared__ short sA[128 * 64];
  __shared__ short sB[128 * 64];
  const int bn = blockIdx.x, bm = blockIdx.y;
  const int tid = threadIdx.x;
  const int wave = tid >> 6, lane = tid & 63;
  const int wm = wave >> 1, wn = wave & 1;
  const int g = lane >> 4, l16 = lane & 15;
  v4f acc[4][4] = {};

  for (int k0 = 0; k0 < K; k0 += 64) {
    __syncthreads();
#pragma unroll
    for (int i = 0; i < 4; ++i) {
      const int c = i * 4 + wave;
      const int e = c * 64 + lane;
      const int row = e >> 3, kof = (e & 7) << 3;
      load_lds16(A  + (size_t)(bm * 128 + row) * K + k0 + kof, &sA[c * 512]);
      load_lds16(Bt + (size_t)(bn * 128 + row) * K + k0 + kof, &sB[c * 512]);
    }
    __syncthreads();
#pragma unroll
    for (int kk = 0; kk < 2; ++kk) {
      v8s fa[4], fb[4];
#pragma unroll
      for (int mi = 0; mi < 4; ++mi)
        fa[mi] = *(const v8s*)&sA[(wm * 64 + mi * 16 + l16) * 64 + kk * 32 + g * 8];
#pragma unroll
      for (int ni = 0; ni < 4; ++ni)
        fb[ni] = *(const v8s*)&sB[(wn * 64 + ni * 16 + l16) * 64 + kk * 32 + g * 8];
#pragma unroll
      for (int mi = 0; mi < 4; ++mi)
#pragma unroll
        for (int ni = 0; ni < 4; ++ni)
          acc[mi][ni] = __builtin_amdgcn_mfma_f32_16x16x32_bf16(fa[mi], fb[ni], acc[mi][ni], 0, 0, 0);
    }
  }
  const int row0 = bm * 128 + wm * 64, col0 = bn * 128 + wn * 64;
#pragma unroll
  for (int mi = 0; mi < 4; ++mi)
#pragma unroll
    for (int ni = 0; ni < 4; ++ni) {
      const int col = col0 + ni * 16 + l16;
      const float bc = bias[col];
#pragma unroll
      for (int r = 0; r < 4; ++r) {
        const int row = row0 + mi * 16 + g * 4 + r;
        const float v = acc[mi][ni][r] + bc;
        if (EPI == 0) {
          ((short*)outp)[(size_t)row * N + col] = f2bf(v * scale);
        } else if (EPI == 1) {
          ((float*)outp)[(size_t)row * N + col] = v;
        } else {
          const float ge = 0.5f * v * (1.0f + erff(v * 0.70710678118654752f));
          ((short*)outp)[(size_t)row * N + col] = f2bf(ge);
        }
      }
    }
}

// ---------------- attention part 1: scores + mask + softmax -> P bf16 [H,NC,128,384] (per batch)
__global__ __launch_bounds__(256)
void att1_k(const short* __restrict__ qg, const short* __restrict__ kg,
            const int* __restrict__ lengths, short* __restrict__ P, int b)
{
  const int half = blockIdx.x & 1, c = blockIdx.x >> 1;
  const int h = blockIdx.y;
  const int len = lengths[b];
  const int wave = threadIdx.x >> 6, lane = threadIdx.x & 63;
  const int g = lane >> 4, l16 = lane & 15;
  const int qtile = half * 64 + wave * 16;
  const short* qp = qg + ((size_t)(b * S_LEN + c * W1_ + qtile + l16) * NHEAD + h) * DHE;
  const v8s a0 = *(const v8s*)(qp + g * 8);
  const v8s a1 = *(const v8s*)(qp + 32 + g * 8);
  v4f s[24];
#pragma unroll
  for (int nt = 0; nt < 24; ++nt) {
    const int jg = c * W1_ - W1_ + nt * 16 + l16;
    const int jc = jg < 0 ? 0 : (jg > S_LEN - 1 ? S_LEN - 1 : jg);
    const short* kp = kg + ((size_t)(b * S_LEN + jc) * NHEAD + h) * DHE;
    v4f t = {0.f, 0.f, 0.f, 0.f};
    t = __builtin_amdgcn_mfma_f32_16x16x32_bf16(a0, *(const v8s*)(kp + g * 8), t, 0, 0, 0);
    t = __builtin_amdgcn_mfma_f32_16x16x32_bf16(a1, *(const v8s*)(kp + 32 + g * 8), t, 0, 0, 0);
    s[nt] = t;
  }
  float sm[4];
#pragma unroll
  for (int r = 0; r < 4; ++r) {
    const int qpos = qtile + g * 4 + r;
    float m = -3.0e38f;
#pragma unroll
    for (int nt = 0; nt < 24; ++nt) {
      const int j = nt * 16 + l16;
      const int jg = c * W1_ - W1_ + j;
      const bool ok = (j >= qpos) & (j <= qpos + 2 * W1_) & (jg >= 0) & (jg < len);
      const float v = ok ? s[nt][r] : -1e9f;
      s[nt][r] = v;
      m = fmaxf(m, v);
    }
#pragma unroll
    for (int d = 1; d < 16; d <<= 1) m = fmaxf(m, __shfl_xor(m, d, 64));
    float su = 0.f;
#pragma unroll
    for (int nt = 0; nt < 24; ++nt) {
      const float e = expf(s[nt][r] - m);
      s[nt][r] = e;
      su += e;
    }
#pragma unroll
    for (int d = 1; d < 16; d <<= 1) su += __shfl_xor(su, d, 64);
    sm[r] = su;
  }
#pragma unroll
  for (int r = 0; r < 4; ++r) {
    const int qpos = qtile + g * 4 + r;
    const int pg = c * W1_ + qpos;
    const float f = (pg < len) ? 1.0f / sm[r] : 0.0f;
    const size_t base = ((size_t)(h * NC_ + c) * W1_ + qpos) * 384;
#pragma unroll
    for (int nt = 0; nt < 24; ++nt)
      P[base + nt * 16 + l16] = f2bf(s[nt][r] * f);
  }
}

// ---------------- attention part 2: ctx = P @ V  (V via transposed vt [B,H,DH,S])
__global__ __launch_bounds__(256)
void att2_k(const short* __restrict__ P, const short* __restrict__ vt,
            short* __restrict__ ctx, int b)
{
  const int c = blockIdx.x, h = blockIdx.y;
  const int wave = threadIdx.x >> 6, lane = threadIdx.x & 63;
  const int g = lane >> 4, l16 = lane & 15;
  v4f acc[2][4] = {};
  const size_t prow0 = (size_t)(h * NC_ + c) * W1_;
  const short* vtb = vt + (size_t)(b * NHEAD + h) * DHE * S_LEN;
#pragma unroll
  for (int kc = 0; kc < 12; ++kc) {
    v8s fa[2], fb[4];
#pragma unroll
    for (int mt = 0; mt < 2; ++mt)
      fa[mt] = *(const v8s*)&P[(prow0 + wave * 32 + mt * 16 + l16) * 384 + kc * 32 + g * 8];
    const int jg = c * W1_ - W1_ + kc * 32 + g * 8;
    const int jc = jg < 0 ? 0 : (jg > S_LEN - 8 ? S_LEN - 8 : jg);
#pragma unroll
    for (int dt = 0; dt < 4; ++dt)
      fb[dt] = *(const v8s*)&vtb[(size_t)(dt * 16 + l16) * S_LEN + jc];
#pragma unroll
    for (int mt = 0; mt < 2; ++mt)
#pragma unroll
      for (int dt = 0; dt < 4; ++dt)
        acc[mt][dt] = __builtin_amdgcn_mfma_f32_16x16x32_bf16(fa[mt], fb[dt], acc[mt][dt], 0, 0, 0);
  }
#pragma unroll
  for (int mt = 0; mt < 2; ++mt)
#pragma unroll
    for (int dt = 0; dt < 4; ++dt)
#pragma unroll
      for (int r = 0; r < 4; ++r) {
        const int srow = c * W1_ + wave * 32 + mt * 16 + g * 4 + r;
        ctx[((size_t)(b * S_LEN + srow) * NHEAD + h) * DHE + dt * 16 + l16] = f2bf(acc[mt][dt][r]);
      }
}

extern "C" void kernel_launch(void* const* d_in, const int* in_sizes, int n_in,
                              void* d_out, int out_size, void* d_ws, size_t ws_size,
                              hipStream_t stream) {
  (void)in_sizes; (void)n_in; (void)out_size; (void)ws_size;
  const float* inputs  = (const float*)d_in[0];
  const int*   lengths = (const int*)d_in[1];
  const float* pos_emb = (const float*)d_in[2];
  const float* tok_emb = (const float*)d_in[3];
  const float* ln_emb_g = (const float*)d_in[4];
  const float* ln_emb_b = (const float*)d_in[5];
  const float* Wq = (const float*)d_in[6];
  const float* bq = (const float*)d_in[7];
  const float* Wk = (const float*)d_in[8];
  const float* bk = (const float*)d_in[9];
  const float* Wv = (const float*)d_in[10];
  const float* bv = (const float*)d_in[11];
  const float* Wo = (const float*)d_in[12];
  const float* bo = (const float*)d_in[13];
  const float* ln1_g = (const float*)d_in[14];
  const float* ln1_b = (const float*)d_in[15];
  const float* Wi = (const float*)d_in[16];
  const float* bi = (const float*)d_in[17];
  const float* Wf = (const float*)d_in[18];
  const float* bf2 = (const float*)d_in[19];
  const float* ln2_g = (const float*)d_in[20];
  const float* ln2_b = (const float*)d_in[21];

  const size_t MTOK = (size_t)2 * S_LEN;     // 8192
  const size_t DD  = (size_t)D_MODEL * D_MODEL;
  const size_t DDF = (size_t)D_MODEL * DFF_;

  char* ws = (char*)d_ws;
  size_t off = 0;
  auto alloc = [&](size_t bytes) { void* p = ws + off; off += (bytes + 255) & ~(size_t)255; return p; };

  short* xb  = (short*)alloc(MTOK * D_MODEL * 2);
  short* qb  = (short*)alloc(MTOK * D_MODEL * 2);
  short* kb  = (short*)alloc(MTOK * D_MODEL * 2);
  short* vb  = (short*)alloc(MTOK * D_MODEL * 2);   // also ctx (vb dead after vtrans)
  short* vtb = (short*)alloc(MTOK * D_MODEL * 2);
  float* y   = (float*)alloc(MTOK * D_MODEL * 4);
  short* Ph  = (short*)alloc((size_t)MTOK * DFF_ * 2);  // 50.3MB: holds P (37.7MB) then h
  short* wqt = (short*)alloc((size_t)NL * DD * 2);
  short* wkt = (short*)alloc((size_t)NL * DD * 2);
  short* wvt = (short*)alloc((size_t)NL * DD * 2);
  short* wot = (short*)alloc((size_t)NL * DD * 2);
  short* wit = (short*)alloc((size_t)NL * DDF * 2);
  short* wft = (short*)alloc((size_t)NL * DDF * 2);
  float* x = (float*)d_out;
  short* ctxb = vb;
  short* hb = Ph;

  const dim3 tb(32, 8);
  transpose_w<<<dim3(24, 24, NL), tb, 0, stream>>>(Wq, wqt, D_MODEL, D_MODEL);
  transpose_w<<<dim3(24, 24, NL), tb, 0, stream>>>(Wk, wkt, D_MODEL, D_MODEL);
  transpose_w<<<dim3(24, 24, NL), tb, 0, stream>>>(Wv, wvt, D_MODEL, D_MODEL);
  transpose_w<<<dim3(24, 24, NL), tb, 0, stream>>>(Wo, wot, D_MODEL, D_MODEL);
  transpose_w<<<dim3(96, 24, NL), tb, 0, stream>>>(Wi, wit, D_MODEL, DFF_);
  transpose_w<<<dim3(24, 96, NL), tb, 0, stream>>>(Wf, wft, DFF_, D_MODEL);

  ln_kernel<0><<<MTOK, 256, 0, stream>>>(inputs, pos_emb, tok_emb, ln_emb_g, ln_emb_b, x, xb);

  for (int l = 0; l < NL; ++l) {
    gemm_bt<0><<<dim3(6, 64), 256, 0, stream>>>(xb, wqt + (size_t)l * DD, bq + l * D_MODEL, qb,
                                                (int)MTOK, D_MODEL, D_MODEL, 0.125f);
    gemm_bt<0><<<dim3(6, 64), 256, 0, stream>>>(xb, wkt + (size_t)l * DD, bk + l * D_MODEL, kb,
                                                (int)MTOK, D_MODEL, D_MODEL, 1.0f);
    gemm_bt<0><<<dim3(6, 64), 256, 0, stream>>>(xb, wvt + (size_t)l * DD, bv + l * D_MODEL, vb,
                                                (int)MTOK, D_MODEL, D_MODEL, 1.0f);
    vtrans<<<dim3(64, NHEAD, 2), dim3(64, 8), 0, stream>>>(vb, vtb);
    for (int b = 0; b < 2; ++b) {
      att1_k<<<dim3(64, NHEAD, 1), 256, 0, stream>>>(qb, kb, lengths, Ph, b);
      att2_k<<<dim3(32, NHEAD, 1), 256, 0, stream>>>(Ph, vtb, ctxb, b);
    }
    gemm_bt<1><<<dim3(6, 64), 256, 0, stream>>>(ctxb, wot + (size_t)l * DD, bo + l * D_MODEL, y,
                                                (int)MTOK, D_MODEL, D_MODEL, 1.0f);
    ln_kernel<1><<<MTOK, 256, 0, stream>>>(x, y, nullptr, ln1_g + l * D_MODEL, ln1_b + l * D_MODEL, x, xb);
    gemm_bt<2><<<dim3(24, 64), 256, 0, stream>>>(xb, wit + (size_t)l * DDF, bi + l * DFF_, hb,
                                                 (int)MTOK, DFF_, D_MODEL, 1.0f);
    gemm_bt<1><<<dim3(6, 64), 256, 0, stream>>>(hb, wft + (size_t)l * DDF, bf2 + l * D_MODEL, y,
                                                (int)MTOK, D_MODEL, DFF_, 1.0f);
    ln_kernel<1><<<MTOK, 256, 0, stream>>>(x, y, nullptr, ln2_g + l * D_MODEL, ln2_b + l * D_MODEL, x, xb);
  }
}

// Round 2
// 1529.776 us; speedup vs baseline: 1.0945x; 1.0945x over previous
//
#include <hip/hip_runtime.h>
#include <cstdint>

#define S_LEN 4096
#define D_MODEL 768
#define NHEAD 12
#define DHE 64
#define DFF_ 3072
#define NL 4
#define W1_ 128
#define NC_ 32
#define QKVN 2304

typedef __attribute__((ext_vector_type(8))) short v8s;
typedef __attribute__((ext_vector_type(4))) float v4f;

__device__ __forceinline__ short f2bf(float f) {
  union { float f; unsigned u; } x; x.f = f;
  unsigned r = x.u + 0x7fffu + ((x.u >> 16) & 1u);
  return (short)(r >> 16);
}

__device__ __forceinline__ void load_lds16(const short* g, short* l) {
  __builtin_amdgcn_global_load_lds((const __attribute__((address_space(1))) void*)g,
                                   (__attribute__((address_space(3))) void*)l, 16, 0, 0);
}

// phase fence: pin all instruction motion at phase boundaries, then HW barrier
#define PFENCE() do { asm volatile("" ::: "memory"); __builtin_amdgcn_sched_barrier(0); __builtin_amdgcn_s_barrier(); } while (0)

// ---- stage one kh-plane (LDS-linear dest, inverse-swizzled global source) ----
// plane layout: [row][32 bf16], row stride 64B, swizzle: byte ^= ((row>>1)&3)<<4
template<int NISS>
__device__ __forceinline__ void stage_plane(const short* __restrict__ gbase, int ldK,
                                            short* lplane, int tid) {
  const int wid = tid >> 6;
#pragma unroll
  for (int r = 0; r < NISS; ++r) {
    const int o = r * 8192 + tid * 16;                     // physical byte in plane
    const int row = o >> 6;
    const int lb = (o & 63) ^ (((row >> 1) & 3) << 4);     // logical byte within row
    const short* g = (const short*)((const char*)gbase + (size_t)row * (size_t)(ldK * 2) + lb);
    short* l = (short*)((char*)lplane + r * 8192 + wid * 1024);
    load_lds16(g, l);
  }
}

__device__ __forceinline__ v8s ldfrag(const short* plane, int row, int g) {
  const int b = (g << 4) ^ (((row >> 1) & 3) << 4);
  return *(const v8s*)((const char*)plane + row * 64 + b);
}

// ---------------- 8-phase 256xBN GEMM: C = A[M,K] @ Bt[N,K]^T + bias ----------------
// EPI 0: bf16 out.  EPI 1: f32 out.  EPI 2: gelu -> bf16.
template<int NF, int EPI>
__global__ __launch_bounds__(512, 2)
void gemm8p(const short* __restrict__ A, const short* __restrict__ Bt,
            const float* __restrict__ bias, void* __restrict__ outp,
            int M, int N, int K)
{
  constexpr int BN = NF * 64;
  constexpr int AN = 2;                      // A plane = 16KB -> 2 issue rounds
  constexpr int BNI = (BN * 64) / 8192;      // B plane issues: 2 (BN=256) or 1 (BN=128)
  __shared__ short sA[2][2][256 * 32];
  __shared__ short sB[2][2][BN * 32];
  const int tid = threadIdx.x;
  const int lane = tid & 63, wid = tid >> 6;
  const int g = lane >> 4, l16 = lane & 15;
  const int wr = wid >> 2, wc = wid & 3;
  const int nt = K >> 6;
  const short* Ab = A + (size_t)(blockIdx.y * 256) * K;
  const short* Bb = Bt + (size_t)(blockIdx.x * BN) * K;

  v4f acc[8][NF] = {};

  // prologue: t0 complete + t1 kh0
  stage_plane<AN >(Ab,      K, &sA[0][0][0], tid);
  stage_plane<BNI>(Bb,      K, &sB[0][0][0], tid);
  stage_plane<AN >(Ab + 32, K, &sA[0][1][0], tid);
  stage_plane<BNI>(Bb + 32, K, &sB[0][1][0], tid);
  stage_plane<AN >(Ab + 64, K, &sA[1][0][0], tid);
  stage_plane<BNI>(Bb + 64, K, &sB[1][0][0], tid);
  if constexpr (NF == 4) asm volatile("s_waitcnt vmcnt(4)");
  else                   asm volatile("s_waitcnt vmcnt(3)");
  __builtin_amdgcn_s_barrier();

  const int arow = wr * 128 + l16;
  const int brow = wc * (NF * 16) + l16;

  for (int t = 0; t < nt; ++t) {
    const int cur = t & 1, nxt = cur ^ 1;
    const short* pA0 = &sA[cur][0][0];
    const short* pA1 = &sA[cur][1][0];
    const short* pB0 = &sB[cur][0][0];
    const short* pB1 = &sB[cur][1][0];
    v8s fa[4], fb[NF];

    // ---- phase a: kk0, m0-3 (+stage t+1 A-kh1 into nxt buf)
#pragma unroll
    for (int m = 0; m < 4; ++m) fa[m] = ldfrag(pA0, arow + m * 16, g);
#pragma unroll
    for (int n = 0; n < NF; ++n) fb[n] = ldfrag(pB0, brow + n * 16, g);
    if (t + 1 < nt) stage_plane<AN>(Ab + (t + 1) * 64 + 32, K, &sA[nxt][1][0], tid);
    PFENCE();
    __builtin_amdgcn_s_setprio(1);
#pragma unroll
    for (int m = 0; m < 4; ++m)
#pragma unroll
      for (int n = 0; n < NF; ++n)
        acc[m][n] = __builtin_amdgcn_mfma_f32_16x16x32_bf16(fa[m], fb[n], acc[m][n], 0, 0, 0);
    __builtin_amdgcn_s_setprio(0);
    PFENCE();

    // ---- phase b: kk0, m4-7 (fb reused; +stage t+1 B-kh1)
#pragma unroll
    for (int m = 0; m < 4; ++m) fa[m] = ldfrag(pA0, arow + 64 + m * 16, g);
    if (t + 1 < nt) stage_plane<BNI>(Bb + (t + 1) * 64 + 32, K, &sB[nxt][1][0], tid);
    PFENCE();
    __builtin_amdgcn_s_setprio(1);
#pragma unroll
    for (int m = 0; m < 4; ++m)
#pragma unroll
      for (int n = 0; n < NF; ++n)
        acc[4 + m][n] = __builtin_amdgcn_mfma_f32_16x16x32_bf16(fa[m], fb[n], acc[4 + m][n], 0, 0, 0);
    __builtin_amdgcn_s_setprio(0);
    PFENCE();

    // ---- phase c: kk1, m0-3 (+stage t+2 A-kh0 into cur buf: region freed after phase b)
#pragma unroll
    for (int m = 0; m < 4; ++m) fa[m] = ldfrag(pA1, arow + m * 16, g);
#pragma unroll
    for (int n = 0; n < NF; ++n) fb[n] = ldfrag(pB1, brow + n * 16, g);
    if (t + 2 < nt) stage_plane<AN>(Ab + (t + 2) * 64, K, &sA[cur][0][0], tid);
    PFENCE();
    __builtin_amdgcn_s_setprio(1);
#pragma unroll
    for (int m = 0; m < 4; ++m)
#pragma unroll
      for (int n = 0; n < NF; ++n)
        acc[m][n] = __builtin_amdgcn_mfma_f32_16x16x32_bf16(fa[m], fb[n], acc[m][n], 0, 0, 0);
    __builtin_amdgcn_s_setprio(0);
    PFENCE();

    // ---- phase d: kk1, m4-7 (+stage t+2 B-kh0; counted vmcnt at tile boundary)
#pragma unroll
    for (int m = 0; m < 4; ++m) fa[m] = ldfrag(pA1, arow + 64 + m * 16, g);
    if (t + 2 < nt) stage_plane<BNI>(Bb + (t + 2) * 64, K, &sB[cur][0][0], tid);
    asm volatile("" ::: "memory");
    __builtin_amdgcn_sched_barrier(0);
    __builtin_amdgcn_s_barrier();
    __builtin_amdgcn_s_setprio(1);
#pragma unroll
    for (int m = 0; m < 4; ++m)
#pragma unroll
      for (int n = 0; n < NF; ++n)
        acc[4 + m][n] = __builtin_amdgcn_mfma_f32_16x16x32_bf16(fa[m], fb[n], acc[4 + m][n], 0, 0, 0);
    __builtin_amdgcn_s_setprio(0);
    asm volatile("" ::: "memory");
    __builtin_amdgcn_sched_barrier(0);
    if (t < nt - 2) {
      if constexpr (NF == 4) asm volatile("s_waitcnt vmcnt(4)");
      else                   asm volatile("s_waitcnt vmcnt(3)");
    } else {
      asm volatile("s_waitcnt vmcnt(0)");
    }
    __builtin_amdgcn_s_barrier();
  }

  // epilogue
  const int row0 = blockIdx.y * 256 + wr * 128;
  const int col0 = blockIdx.x * BN + wc * NF * 16;
#pragma unroll
  for (int m = 0; m < 8; ++m)
#pragma unroll
    for (int n = 0; n < NF; ++n) {
      const int col = col0 + n * 16 + l16;
      const float bc = bias[col];
#pragma unroll
      for (int r = 0; r < 4; ++r) {
        const int row = row0 + m * 16 + g * 4 + r;
        const float v = acc[m][n][r] + bc;
        if (EPI == 0) {
          ((short*)outp)[(size_t)row * N + col] = f2bf(v);
        } else if (EPI == 1) {
          ((float*)outp)[(size_t)row * N + col] = v;
        } else {
          const float e = __expf(1.5957691216057308f * (v + 0.044715f * v * v * v));
          ((short*)outp)[(size_t)row * N + col] = f2bf(v - v / (1.0f + e));
        }
      }
    }
}

// ---------------- weight transpose f32[K,N] -> bf16[N,K] (with scale fold) ----------------
__global__ __launch_bounds__(256)
void transpose_w(const float* __restrict__ in, short* __restrict__ out, int K, int N,
                 size_t in_ls, size_t out_ls, float scale)
{
  __shared__ float t[32][33];
  const int n0 = blockIdx.x * 32, k0 = blockIdx.y * 32;
  const float* src = in + (size_t)blockIdx.z * in_ls;
  short* dst = out + (size_t)blockIdx.z * out_ls;
  const int tx = threadIdx.x, ty = threadIdx.y;   // (32,8)
#pragma unroll
  for (int i = 0; i < 4; ++i)
    t[ty + 8*i][tx] = src[(size_t)(k0 + ty + 8*i) * N + n0 + tx];
  __syncthreads();
#pragma unroll
  for (int i = 0; i < 4; ++i)
    dst[(size_t)(n0 + ty + 8*i) * K + k0 + tx] = f2bf(t[tx][ty + 8*i] * scale);
}

__global__ void prep_bias(const float* __restrict__ bq, const float* __restrict__ bk,
                          const float* __restrict__ bv, float* __restrict__ out)
{
  const int l = blockIdx.x, p = blockIdx.y, c = threadIdx.x;
  const float* s = p == 0 ? bq : (p == 1 ? bk : bv);
  out[(l * 3 + p) * 768 + c] = s[l * 768 + c] * (p == 0 ? 0.125f : 1.0f);
}

// ---------------- V transpose: qkv[B,S,2304] v-part -> vt [B,H,DH,S] ----------------
__global__ __launch_bounds__(512)
void vtrans(const short* __restrict__ qkv, short* __restrict__ vt)
{
  __shared__ short t[64][65];
  const int s0 = blockIdx.x * 64, h = blockIdx.y, b = blockIdx.z;
  const int tx = threadIdx.x, ty = threadIdx.y;   // (64,8)
#pragma unroll
  for (int i = 0; i < 8; ++i)
    t[ty + 8*i][tx] = qkv[(size_t)(b * S_LEN + s0 + ty + 8*i) * QKVN + 1536 + h * DHE + tx];
  __syncthreads();
#pragma unroll
  for (int i = 0; i < 8; ++i)
    vt[((size_t)(b * NHEAD + h) * DHE + ty + 8*i) * S_LEN + s0 + tx] = t[tx][ty + 8*i];
}

// ---------------- LayerNorm. MODE 0: embed (in0 + pos + tok), MODE 1: residual ----------------
template<int MODE>
__global__ __launch_bounds__(256)
void ln_kernel(const float* __restrict__ in0, const float* __restrict__ in1,
               const float* __restrict__ in2,
               const float* __restrict__ gamma, const float* __restrict__ beta,
               float* __restrict__ outf, short* __restrict__ outb)
{
  __shared__ float red[8];
  const int row = blockIdx.x;
  const int tid = threadIdx.x;
  const int wave = tid >> 6, lane = tid & 63;
  float v[3];
#pragma unroll
  for (int i = 0; i < 3; ++i) {
    const int c = tid + i * 256;
    const size_t idx = (size_t)row * D_MODEL + c;
    if (MODE == 0) {
      const int s = row & (S_LEN - 1);
      v[i] = in0[idx] + in1[(size_t)(2 + s) * D_MODEL + c] + in2[c];
    } else {
      v[i] = in0[idx] + in1[idx];
    }
  }
  float sum = v[0] + v[1] + v[2];
#pragma unroll
  for (int m = 1; m < 64; m <<= 1) sum += __shfl_xor(sum, m, 64);
  if (lane == 0) red[wave] = sum;
  __syncthreads();
  const float mean = (red[0] + red[1] + red[2] + red[3]) * (1.0f / 768.0f);
  float sq = 0.f;
#pragma unroll
  for (int i = 0; i < 3; ++i) { float d = v[i] - mean; sq += d * d; }
#pragma unroll
  for (int m = 1; m < 64; m <<= 1) sq += __shfl_xor(sq, m, 64);
  if (lane == 0) red[4 + wave] = sq;
  __syncthreads();
  const float var = (red[4] + red[5] + red[6] + red[7]) * (1.0f / 768.0f);
  const float rstd = 1.0f / sqrtf(var + 1e-12f);
#pragma unroll
  for (int i = 0; i < 3; ++i) {
    const int c = tid + i * 256;
    const size_t idx = (size_t)row * D_MODEL + c;
    const float o = (v[i] - mean) * rstd * gamma[c] + beta[c];
    outf[idx] = o;
    outb[idx] = f2bf(o);
  }
}

// ---------------- attention part 1: scores + mask + softmax -> P bf16 [H,NC,128,384] ----------------
__global__ __launch_bounds__(256)
void att1_k(const short* __restrict__ qkv, const int* __restrict__ lengths,
            short* __restrict__ P, int b)
{
  const int half = blockIdx.x & 1, c = blockIdx.x >> 1;
  const int h = blockIdx.y;
  const int len = lengths[b];
  const int wave = threadIdx.x >> 6, lane = threadIdx.x & 63;
  const int g = lane >> 4, l16 = lane & 15;
  const int qtile = half * 64 + wave * 16;
  const short* qp = qkv + (size_t)(b * S_LEN + c * W1_ + qtile + l16) * QKVN + h * DHE;
  const v8s a0 = *(const v8s*)(qp + g * 8);
  const v8s a1 = *(const v8s*)(qp + 32 + g * 8);
  v4f s[24];
#pragma unroll
  for (int nt = 0; nt < 24; ++nt) {
    const int jg = c * W1_ - W1_ + nt * 16 + l16;
    const int jc = jg < 0 ? 0 : (jg > S_LEN - 1 ? S_LEN - 1 : jg);
    const short* kp = qkv + (size_t)(b * S_LEN + jc) * QKVN + 768 + h * DHE;
    v4f t = {0.f, 0.f, 0.f, 0.f};
    t = __builtin_amdgcn_mfma_f32_16x16x32_bf16(a0, *(const v8s*)(kp + g * 8), t, 0, 0, 0);
    t = __builtin_amdgcn_mfma_f32_16x16x32_bf16(a1, *(const v8s*)(kp + 32 + g * 8), t, 0, 0, 0);
    s[nt] = t;
  }
  float sm[4];
#pragma unroll
  for (int r = 0; r < 4; ++r) {
    const int qpos = qtile + g * 4 + r;
    float m = -3.0e38f;
#pragma unroll
    for (int nt = 0; nt < 24; ++nt) {
      const int j = nt * 16 + l16;
      const int jg = c * W1_ - W1_ + j;
      const bool ok = (j >= qpos) & (j <= qpos + 2 * W1_) & (jg >= 0) & (jg < len);
      const float v = ok ? s[nt][r] : -1e9f;
      s[nt][r] = v;
      m = fmaxf(m, v);
    }
#pragma unroll
    for (int d = 1; d < 16; d <<= 1) m = fmaxf(m, __shfl_xor(m, d, 64));
    float su = 0.f;
#pragma unroll
    for (int nt = 0; nt < 24; ++nt) {
      const float e = __expf(s[nt][r] - m);
      s[nt][r] = e;
      su += e;
    }
#pragma unroll
    for (int d = 1; d < 16; d <<= 1) su += __shfl_xor(su, d, 64);
    sm[r] = su;
  }
#pragma unroll
  for (int r = 0; r < 4; ++r) {
    const int qpos = qtile + g * 4 + r;
    const int pg = c * W1_ + qpos;
    const float f = (pg < len) ? 1.0f / sm[r] : 0.0f;
    const size_t base = ((size_t)(h * NC_ + c) * W1_ + qpos) * 384;
#pragma unroll
    for (int nt = 0; nt < 24; ++nt)
      P[base + nt * 16 + l16] = f2bf(s[nt][r] * f);
  }
}

// ---------------- attention part 2: ctx = P @ V ----------------
__global__ __launch_bounds__(256)
void att2_k(const short* __restrict__ P, const short* __restrict__ vt,
            short* __restrict__ ctx, int b)
{
  const int c = blockIdx.x, h = blockIdx.y;
  const int wave = threadIdx.x >> 6, lane = threadIdx.x & 63;
  const int g = lane >> 4, l16 = lane & 15;
  v4f acc[2][4] = {};
  const size_t prow0 = (size_t)(h * NC_ + c) * W1_;
  const short* vtb = vt + (size_t)(b * NHEAD + h) * DHE * S_LEN;
#pragma unroll
  for (int kc = 0; kc < 12; ++kc) {
    v8s fa[2], fb[4];
#pragma unroll
    for (int mt = 0; mt < 2; ++mt)
      fa[mt] = *(const v8s*)&P[(prow0 + wave * 32 + mt * 16 + l16) * 384 + kc * 32 + g * 8];
    const int jg = c * W1_ - W1_ + kc * 32 + g * 8;
    const int jc = jg < 0 ? 0 : (jg > S_LEN - 8 ? S_LEN - 8 : jg);
#pragma unroll
    for (int dt = 0; dt < 4; ++dt)
      fb[dt] = *(const v8s*)&vtb[(size_t)(dt * 16 + l16) * S_LEN + jc];
#pragma unroll
    for (int mt = 0; mt < 2; ++mt)
#pragma unroll
      for (int dt = 0; dt < 4; ++dt)
        acc[mt][dt] = __builtin_amdgcn_mfma_f32_16x16x32_bf16(fa[mt], fb[dt], acc[mt][dt], 0, 0, 0);
  }
#pragma unroll
  for (int mt = 0; mt < 2; ++mt)
#pragma unroll
    for (int dt = 0; dt < 4; ++dt)
#pragma unroll
      for (int r = 0; r < 4; ++r) {
        const int srow = c * W1_ + wave * 32 + mt * 16 + g * 4 + r;
        ctx[((size_t)(b * S_LEN + srow) * NHEAD + h) * DHE + dt * 16 + l16] = f2bf(acc[mt][dt][r]);
      }
}

extern "C" void kernel_launch(void* const* d_in, const int* in_sizes, int n_in,
                              void* d_out, int out_size, void* d_ws, size_t ws_size,
                              hipStream_t stream) {
  (void)in_sizes; (void)n_in; (void)out_size; (void)ws_size;
  const float* inputs  = (const float*)d_in[0];
  const int*   lengths = (const int*)d_in[1];
  const float* pos_emb = (const float*)d_in[2];
  const float* tok_emb = (const float*)d_in[3];
  const float* ln_emb_g = (const float*)d_in[4];
  const float* ln_emb_b = (const float*)d_in[5];
  const float* Wq = (const float*)d_in[6];
  const float* bq = (const float*)d_in[7];
  const float* Wk = (const float*)d_in[8];
  const float* bk = (const float*)d_in[9];
  const float* Wv = (const float*)d_in[10];
  const float* bv = (const float*)d_in[11];
  const float* Wo = (const float*)d_in[12];
  const float* bo = (const float*)d_in[13];
  const float* ln1_g = (const float*)d_in[14];
  const float* ln1_b = (const float*)d_in[15];
  const float* Wi = (const float*)d_in[16];
  const float* bi = (const float*)d_in[17];
  const float* Wf = (const float*)d_in[18];
  const float* bf2 = (const float*)d_in[19];
  const float* ln2_g = (const float*)d_in[20];
  const float* ln2_b = (const float*)d_in[21];

  const size_t MTOK = (size_t)2 * S_LEN;     // 8192
  const size_t DD  = (size_t)D_MODEL * D_MODEL;
  const size_t DDF = (size_t)D_MODEL * DFF_;

  char* ws = (char*)d_ws;
  size_t off = 0;
  auto alloc = [&](size_t bytes) { void* p = ws + off; off += (bytes + 255) & ~(size_t)255; return p; };

  short* xb    = (short*)alloc(MTOK * D_MODEL * 2);
  short* qkv   = (short*)alloc(MTOK * QKVN * 2);
  short* vtb   = (short*)alloc(MTOK * D_MODEL * 2);
  float* y     = (float*)alloc(MTOK * D_MODEL * 4);
  short* Ph    = (short*)alloc(MTOK * DFF_ * 2);   // P (37.75MB) + ctx (12.58MB); later h
  short* wqkvt = (short*)alloc((size_t)NL * QKVN * D_MODEL * 2);
  short* wot   = (short*)alloc((size_t)NL * DD * 2);
  short* wit   = (short*)alloc((size_t)NL * DDF * 2);
  short* wft   = (short*)alloc((size_t)NL * DDF * 2);
  float* bqkv  = (float*)alloc((size_t)NL * QKVN * 4);
  float* x = (float*)d_out;
  short* ctxb = Ph + (size_t)NHEAD * NC_ * W1_ * 384;  // 18874368 elems
  short* hb = Ph;

  const dim3 tb(32, 8);
  const size_t QL = (size_t)QKVN * D_MODEL;
  transpose_w<<<dim3(24, 24, NL), tb, 0, stream>>>(Wq, wqkvt,            D_MODEL, D_MODEL, DD, QL, 0.125f);
  transpose_w<<<dim3(24, 24, NL), tb, 0, stream>>>(Wk, wqkvt + 768*768,  D_MODEL, D_MODEL, DD, QL, 1.0f);
  transpose_w<<<dim3(24, 24, NL), tb, 0, stream>>>(Wv, wqkvt + 1536*768, D_MODEL, D_MODEL, DD, QL, 1.0f);
  transpose_w<<<dim3(24, 24, NL), tb, 0, stream>>>(Wo, wot, D_MODEL, D_MODEL, DD, DD, 1.0f);
  transpose_w<<<dim3(96, 24, NL), tb, 0, stream>>>(Wi, wit, D_MODEL, DFF_, DDF, DDF, 1.0f);
  transpose_w<<<dim3(24, 96, NL), tb, 0, stream>>>(Wf, wft, DFF_, D_MODEL, DDF, DDF, 1.0f);
  prep_bias<<<dim3(NL, 3), 768, 0, stream>>>(bq, bk, bv, bqkv);

  ln_kernel<0><<<MTOK, 256, 0, stream>>>(inputs, pos_emb, tok_emb, ln_emb_g, ln_emb_b, x, xb);

  for (int l = 0; l < NL; ++l) {
    gemm8p<4, 0><<<dim3(9, 32), 512, 0, stream>>>(xb, wqkvt + (size_t)l * QL, bqkv + (size_t)l * QKVN,
                                                  qkv, (int)MTOK, QKVN, D_MODEL);
    vtrans<<<dim3(64, NHEAD, 2), dim3(64, 8), 0, stream>>>(qkv, vtb);
    for (int b = 0; b < 2; ++b) {
      att1_k<<<dim3(64, NHEAD, 1), 256, 0, stream>>>(qkv, lengths, Ph, b);
      att2_k<<<dim3(32, NHEAD, 1), 256, 0, stream>>>(Ph, vtb, ctxb, b);
    }
    gemm8p<2, 1><<<dim3(6, 32), 512, 0, stream>>>(ctxb, wot + (size_t)l * DD, bo + l * D_MODEL,
                                                  y, (int)MTOK, D_MODEL, D_MODEL);
    ln_kernel<1><<<MTOK, 256, 0, stream>>>(x, y, nullptr, ln1_g + l * D_MODEL, ln1_b + l * D_MODEL, x, xb);
    gemm8p<4, 2><<<dim3(12, 32), 512, 0, stream>>>(xb, wit + (size_t)l * DDF, bi + l * DFF_,
                                                   hb, (int)MTOK, DFF_, D_MODEL);
    gemm8p<2, 1><<<dim3(6, 32), 512, 0, stream>>>(hb, wft + (size_t)l * DDF, bf2 + l * D_MODEL,
                                                  y, (int)MTOK, D_MODEL, DFF_);
    ln_kernel<1><<<MTOK, 256, 0, stream>>>(x, y, nullptr, ln2_g + l * D_MODEL, ln2_b + l * D_MODEL, x, xb);
  }
}

// Round 3
// 1372.147 us; speedup vs baseline: 1.2202x; 1.1149x over previous
//
#include <hip/hip_runtime.h>
#include <cstdint>

#define S_LEN 4096
#define D_MODEL 768
#define NHEAD 12
#define DHE 64
#define DFF_ 3072
#define NL 4
#define W1_ 128
#define NC_ 32
#define QKVN 2304

typedef __attribute__((ext_vector_type(8))) short v8s;
typedef __attribute__((ext_vector_type(4))) float v4f;

__device__ __forceinline__ short f2bf(float f) {
  union { float f; unsigned u; } x; x.f = f;
  unsigned r = x.u + 0x7fffu + ((x.u >> 16) & 1u);
  return (short)(r >> 16);
}

__device__ __forceinline__ void load_lds16(const short* g, short* l) {
  __builtin_amdgcn_global_load_lds((const __attribute__((address_space(1))) void*)g,
                                   (__attribute__((address_space(3))) void*)l, 16, 0, 0);
}

// phase fence: pin all instruction motion at phase boundaries, then HW barrier
#define PFENCE() do { asm volatile("" ::: "memory"); __builtin_amdgcn_sched_barrier(0); __builtin_amdgcn_s_barrier(); } while (0)

// ---- stage one kh-plane (LDS-linear dest, inverse-swizzled global source) ----
// plane layout: [row][32 bf16], row stride 64B, swizzle: byte ^= ((row>>1)&3)<<4
template<int NISS>
__device__ __forceinline__ void stage_plane(const short* __restrict__ gbase, int ldK,
                                            short* lplane, int tid) {
  const int wid = tid >> 6;
#pragma unroll
  for (int r = 0; r < NISS; ++r) {
    const int o = r * 8192 + tid * 16;                     // physical byte in plane
    const int row = o >> 6;
    const int lb = (o & 63) ^ (((row >> 1) & 3) << 4);     // logical byte within row
    const short* g = (const short*)((const char*)gbase + (size_t)row * (size_t)(ldK * 2) + lb);
    short* l = (short*)((char*)lplane + r * 8192 + wid * 1024);
    load_lds16(g, l);
  }
}

__device__ __forceinline__ v8s ldfrag(const short* plane, int row, int g) {
  const int b = (g << 4) ^ (((row >> 1) & 3) << 4);
  return *(const v8s*)((const char*)plane + row * 64 + b);
}

// ---------------- 8-phase 256xBN GEMM: C = A[M,K] @ Bt[N,K]^T + bias ----------------
// EPI 0: bf16 out.  EPI 1: f32 out.  EPI 2: gelu -> bf16.
template<int NF, int EPI>
__global__ __launch_bounds__(512, 2)
void gemm8p(const short* __restrict__ A, const short* __restrict__ Bt,
            const float* __restrict__ bias, void* __restrict__ outp,
            int M, int N, int K)
{
  constexpr int BN = NF * 64;
  constexpr int AN = 2;                      // A plane = 16KB -> 2 issue rounds
  constexpr int BNI = (BN * 64) / 8192;      // B plane issues: 2 (BN=256) or 1 (BN=128)
  __shared__ short sA[2][2][256 * 32];
  __shared__ short sB[2][2][BN * 32];
  const int tid = threadIdx.x;
  const int lane = tid & 63, wid = tid >> 6;
  const int g = lane >> 4, l16 = lane & 15;
  const int wr = wid >> 2, wc = wid & 3;
  const int nt = K >> 6;

  // XCD-bijective swizzle (m204): physical id p -> logical lb, contiguous per XCD.
  // bn-fastest within the XCD chunk => same-bm blocks co-resident on one XCD L2.
  const int gx = gridDim.x;
  const int nwg = gx * gridDim.y;
  const int p = blockIdx.y * gx + blockIdx.x;
  const int q8 = nwg >> 3, r8 = nwg & 7;
  const int xcd = p & 7, wi = p >> 3;
  const int lb = (xcd < r8 ? xcd * (q8 + 1) : r8 * (q8 + 1) + (xcd - r8) * q8) + wi;
  const int bn_ = lb % gx, bm_ = lb / gx;

  const short* Ab = A + (size_t)(bm_ * 256) * K;
  const short* Bb = Bt + (size_t)(bn_ * BN) * K;

  v4f acc[8][NF] = {};

  // prologue: t0 complete + t1 kh0
  stage_plane<AN >(Ab,      K, &sA[0][0][0], tid);
  stage_plane<BNI>(Bb,      K, &sB[0][0][0], tid);
  stage_plane<AN >(Ab + 32, K, &sA[0][1][0], tid);
  stage_plane<BNI>(Bb + 32, K, &sB[0][1][0], tid);
  stage_plane<AN >(Ab + 64, K, &sA[1][0][0], tid);
  stage_plane<BNI>(Bb + 64, K, &sB[1][0][0], tid);
  if constexpr (NF == 4) asm volatile("s_waitcnt vmcnt(4)");
  else                   asm volatile("s_waitcnt vmcnt(3)");
  __builtin_amdgcn_s_barrier();

  const int arow = wr * 128 + l16;
  const int brow = wc * (NF * 16) + l16;

  for (int t = 0; t < nt; ++t) {
    const int cur = t & 1, nxt = cur ^ 1;
    const short* pA0 = &sA[cur][0][0];
    const short* pA1 = &sA[cur][1][0];
    const short* pB0 = &sB[cur][0][0];
    const short* pB1 = &sB[cur][1][0];
    v8s fa[4], fb[NF];

    // ---- phase a: kk0, m0-3 (+stage t+1 A-kh1 into nxt buf)
#pragma unroll
    for (int m = 0; m < 4; ++m) fa[m] = ldfrag(pA0, arow + m * 16, g);
#pragma unroll
    for (int n = 0; n < NF; ++n) fb[n] = ldfrag(pB0, brow + n * 16, g);
    if (t + 1 < nt) stage_plane<AN>(Ab + (t + 1) * 64 + 32, K, &sA[nxt][1][0], tid);
    PFENCE();
    __builtin_amdgcn_s_setprio(1);
#pragma unroll
    for (int m = 0; m < 4; ++m)
#pragma unroll
      for (int n = 0; n < NF; ++n)
        acc[m][n] = __builtin_amdgcn_mfma_f32_16x16x32_bf16(fa[m], fb[n], acc[m][n], 0, 0, 0);
    __builtin_amdgcn_s_setprio(0);
    PFENCE();

    // ---- phase b: kk0, m4-7 (fb reused; +stage t+1 B-kh1)
#pragma unroll
    for (int m = 0; m < 4; ++m) fa[m] = ldfrag(pA0, arow + 64 + m * 16, g);
    if (t + 1 < nt) stage_plane<BNI>(Bb + (t + 1) * 64 + 32, K, &sB[nxt][1][0], tid);
    PFENCE();
    __builtin_amdgcn_s_setprio(1);
#pragma unroll
    for (int m = 0; m < 4; ++m)
#pragma unroll
      for (int n = 0; n < NF; ++n)
        acc[4 + m][n] = __builtin_amdgcn_mfma_f32_16x16x32_bf16(fa[m], fb[n], acc[4 + m][n], 0, 0, 0);
    __builtin_amdgcn_s_setprio(0);
    PFENCE();

    // ---- phase c: kk1, m0-3 (+stage t+2 A-kh0 into cur buf: region freed after phase b)
#pragma unroll
    for (int m = 0; m < 4; ++m) fa[m] = ldfrag(pA1, arow + m * 16, g);
#pragma unroll
    for (int n = 0; n < NF; ++n) fb[n] = ldfrag(pB1, brow + n * 16, g);
    if (t + 2 < nt) stage_plane<AN>(Ab + (t + 2) * 64, K, &sA[cur][0][0], tid);
    PFENCE();
    __builtin_amdgcn_s_setprio(1);
#pragma unroll
    for (int m = 0; m < 4; ++m)
#pragma unroll
      for (int n = 0; n < NF; ++n)
        acc[m][n] = __builtin_amdgcn_mfma_f32_16x16x32_bf16(fa[m], fb[n], acc[m][n], 0, 0, 0);
    __builtin_amdgcn_s_setprio(0);
    PFENCE();

    // ---- phase d: kk1, m4-7 (+stage t+2 B-kh0; counted vmcnt at tile boundary)
#pragma unroll
    for (int m = 0; m < 4; ++m) fa[m] = ldfrag(pA1, arow + 64 + m * 16, g);
    if (t + 2 < nt) stage_plane<BNI>(Bb + (t + 2) * 64, K, &sB[cur][0][0], tid);
    asm volatile("" ::: "memory");
    __builtin_amdgcn_sched_barrier(0);
    __builtin_amdgcn_s_barrier();
    __builtin_amdgcn_s_setprio(1);
#pragma unroll
    for (int m = 0; m < 4; ++m)
#pragma unroll
      for (int n = 0; n < NF; ++n)
        acc[4 + m][n] = __builtin_amdgcn_mfma_f32_16x16x32_bf16(fa[m], fb[n], acc[4 + m][n], 0, 0, 0);
    __builtin_amdgcn_s_setprio(0);
    asm volatile("" ::: "memory");
    __builtin_amdgcn_sched_barrier(0);
    if (t < nt - 2) {
      if constexpr (NF == 4) asm volatile("s_waitcnt vmcnt(4)");
      else                   asm volatile("s_waitcnt vmcnt(3)");
    } else {
      asm volatile("s_waitcnt vmcnt(0)");
    }
    __builtin_amdgcn_s_barrier();
  }

  // epilogue
  const int row0 = bm_ * 256 + wr * 128;
  const int col0 = bn_ * BN + wc * NF * 16;
#pragma unroll
  for (int m = 0; m < 8; ++m)
#pragma unroll
    for (int n = 0; n < NF; ++n) {
      const int col = col0 + n * 16 + l16;
      const float bc = bias[col];
#pragma unroll
      for (int r = 0; r < 4; ++r) {
        const int row = row0 + m * 16 + g * 4 + r;
        const float v = acc[m][n][r] + bc;
        if (EPI == 0) {
          ((short*)outp)[(size_t)row * N + col] = f2bf(v);
        } else if (EPI == 1) {
          ((float*)outp)[(size_t)row * N + col] = v;
        } else {
          const float e = __expf(1.5957691216057308f * (v + 0.044715f * v * v * v));
          ((short*)outp)[(size_t)row * N + col] = f2bf(v - v / (1.0f + e));
        }
      }
    }
}

// ---------------- weight transpose f32[K,N] -> bf16[N,K] (with scale fold) ----------------
__global__ __launch_bounds__(256)
void transpose_w(const float* __restrict__ in, short* __restrict__ out, int K, int N,
                 size_t in_ls, size_t out_ls, float scale)
{
  __shared__ float t[32][33];
  const int n0 = blockIdx.x * 32, k0 = blockIdx.y * 32;
  const float* src = in + (size_t)blockIdx.z * in_ls;
  short* dst = out + (size_t)blockIdx.z * out_ls;
  const int tx = threadIdx.x, ty = threadIdx.y;   // (32,8)
#pragma unroll
  for (int i = 0; i < 4; ++i)
    t[ty + 8*i][tx] = src[(size_t)(k0 + ty + 8*i) * N + n0 + tx];
  __syncthreads();
#pragma unroll
  for (int i = 0; i < 4; ++i)
    dst[(size_t)(n0 + ty + 8*i) * K + k0 + tx] = f2bf(t[tx][ty + 8*i] * scale);
}

__global__ void prep_bias(const float* __restrict__ bq, const float* __restrict__ bk,
                          const float* __restrict__ bv, float* __restrict__ out)
{
  const int l = blockIdx.x, p = blockIdx.y, c = threadIdx.x;
  const float* s = p == 0 ? bq : (p == 1 ? bk : bv);
  out[(l * 3 + p) * 768 + c] = s[l * 768 + c] * (p == 0 ? 0.125f : 1.0f);
}

// ---------------- V transpose: qkv[B,S,2304] v-part -> vt [B,H,DH,S] ----------------
__global__ __launch_bounds__(512)
void vtrans(const short* __restrict__ qkv, short* __restrict__ vt)
{
  __shared__ short t[64][65];
  const int s0 = blockIdx.x * 64, h = blockIdx.y, b = blockIdx.z;
  const int tx = threadIdx.x, ty = threadIdx.y;   // (64,8)
#pragma unroll
  for (int i = 0; i < 8; ++i)
    t[ty + 8*i][tx] = qkv[(size_t)(b * S_LEN + s0 + ty + 8*i) * QKVN + 1536 + h * DHE + tx];
  __syncthreads();
#pragma unroll
  for (int i = 0; i < 8; ++i)
    vt[((size_t)(b * NHEAD + h) * DHE + ty + 8*i) * S_LEN + s0 + tx] = t[tx][ty + 8*i];
}

// ---------------- LayerNorm. MODE 0: embed (in0 + pos + tok), MODE 1: residual ----------------
template<int MODE>
__global__ __launch_bounds__(256)
void ln_kernel(const float* __restrict__ in0, const float* __restrict__ in1,
               const float* __restrict__ in2,
               const float* __restrict__ gamma, const float* __restrict__ beta,
               float* __restrict__ outf, short* __restrict__ outb)
{
  __shared__ float red[8];
  const int row = blockIdx.x;
  const int tid = threadIdx.x;
  const int wave = tid >> 6, lane = tid & 63;
  float v[3];
#pragma unroll
  for (int i = 0; i < 3; ++i) {
    const int c = tid + i * 256;
    const size_t idx = (size_t)row * D_MODEL + c;
    if (MODE == 0) {
      const int s = row & (S_LEN - 1);
      v[i] = in0[idx] + in1[(size_t)(2 + s) * D_MODEL + c] + in2[c];
    } else {
      v[i] = in0[idx] + in1[idx];
    }
  }
  float sum = v[0] + v[1] + v[2];
#pragma unroll
  for (int m = 1; m < 64; m <<= 1) sum += __shfl_xor(sum, m, 64);
  if (lane == 0) red[wave] = sum;
  __syncthreads();
  const float mean = (red[0] + red[1] + red[2] + red[3]) * (1.0f / 768.0f);
  float sq = 0.f;
#pragma unroll
  for (int i = 0; i < 3; ++i) { float d = v[i] - mean; sq += d * d; }
#pragma unroll
  for (int m = 1; m < 64; m <<= 1) sq += __shfl_xor(sq, m, 64);
  if (lane == 0) red[4 + wave] = sq;
  __syncthreads();
  const float var = (red[4] + red[5] + red[6] + red[7]) * (1.0f / 768.0f);
  const float rstd = 1.0f / sqrtf(var + 1e-12f);
#pragma unroll
  for (int i = 0; i < 3; ++i) {
    const int c = tid + i * 256;
    const size_t idx = (size_t)row * D_MODEL + c;
    const float o = (v[i] - mean) * rstd * gamma[c] + beta[c];
    outf[idx] = o;
    outb[idx] = f2bf(o);
  }
}

// ---------------- fused attention: QK^T -> softmax -> P(LDS) -> PV ----------------
// grid (64 = b*32+c, NHEAD), 512 threads (8 waves x 16 q-rows).
// P LDS [128][384] bf16, swizzled byte ^= ((q>>1)&7)<<4 within the 768B row.
__device__ __forceinline__ int pswz(int q, int kbyte) {
  return q * 768 + (kbyte ^ (((q >> 1) & 7) << 4));
}

__global__ __launch_bounds__(512)
void att_fused(const short* __restrict__ qkv, const short* __restrict__ vt,
               const int* __restrict__ lengths, short* __restrict__ ctx)
{
  __shared__ short Pl[128 * 384];
  const int b = blockIdx.x >> 5, c = blockIdx.x & 31;
  const int h = blockIdx.y;
  const int len = lengths[b];
  const int wave = threadIdx.x >> 6, lane = threadIdx.x & 63;
  const int g = lane >> 4, l16 = lane & 15;
  const int qtile = wave * 16;

  // ---- QK^T for 16 q-rows of this wave
  const short* qp = qkv + (size_t)(b * S_LEN + c * W1_ + qtile + l16) * QKVN + h * DHE;
  const v8s a0 = *(const v8s*)(qp + g * 8);
  const v8s a1 = *(const v8s*)(qp + 32 + g * 8);
  v4f s[24];
#pragma unroll
  for (int nt = 0; nt < 24; ++nt) {
    const int jg = c * W1_ - W1_ + nt * 16 + l16;
    const int jc = jg < 0 ? 0 : (jg > S_LEN - 1 ? S_LEN - 1 : jg);
    const short* kp = qkv + (size_t)(b * S_LEN + jc) * QKVN + 768 + h * DHE;
    v4f t = {0.f, 0.f, 0.f, 0.f};
    t = __builtin_amdgcn_mfma_f32_16x16x32_bf16(a0, *(const v8s*)(kp + g * 8), t, 0, 0, 0);
    t = __builtin_amdgcn_mfma_f32_16x16x32_bf16(a1, *(const v8s*)(kp + 32 + g * 8), t, 0, 0, 0);
    s[nt] = t;
  }
  // ---- mask + softmax (row reduce within 16-lane group) + write P to LDS
#pragma unroll
  for (int r = 0; r < 4; ++r) {
    const int qpos = qtile + g * 4 + r;
    float m = -3.0e38f;
#pragma unroll
    for (int nt = 0; nt < 24; ++nt) {
      const int j = nt * 16 + l16;
      const int jg = c * W1_ - W1_ + j;
      const bool ok = (j >= qpos) & (j <= qpos + 2 * W1_) & (jg >= 0) & (jg < len);
      const float v = ok ? s[nt][r] : -1e9f;
      s[nt][r] = v;
      m = fmaxf(m, v);
    }
#pragma unroll
    for (int d = 1; d < 16; d <<= 1) m = fmaxf(m, __shfl_xor(m, d, 64));
    float su = 0.f;
#pragma unroll
    for (int nt = 0; nt < 24; ++nt) {
      const float e = __expf(s[nt][r] - m);
      s[nt][r] = e;
      su += e;
    }
#pragma unroll
    for (int d = 1; d < 16; d <<= 1) su += __shfl_xor(su, d, 64);
    const float f = (c * W1_ + qpos < len) ? 1.0f / su : 0.0f;
#pragma unroll
    for (int nt = 0; nt < 24; ++nt)
      *(short*)((char*)Pl + pswz(qpos, (nt * 16 + l16) * 2)) = f2bf(s[nt][r] * f);
  }
  __syncthreads();

  // ---- PV: this wave's 16 q-rows x 64 d, K=384
  v4f acc[4] = {};
  const short* vtb = vt + (size_t)(b * NHEAD + h) * DHE * S_LEN;
#pragma unroll
  for (int kc = 0; kc < 12; ++kc) {
    const v8s fa = *(const v8s*)((char*)Pl + pswz(qtile + l16, kc * 64 + g * 16));
    const int jg = c * W1_ - W1_ + kc * 32 + g * 8;
    const int jc = jg < 0 ? 0 : (jg > S_LEN - 8 ? S_LEN - 8 : jg);
#pragma unroll
    for (int dt = 0; dt < 4; ++dt) {
      const v8s fb = *(const v8s*)&vtb[(size_t)(dt * 16 + l16) * S_LEN + jc];
      acc[dt] = __builtin_amdgcn_mfma_f32_16x16x32_bf16(fa, fb, acc[dt], 0, 0, 0);
    }
  }
#pragma unroll
  for (int dt = 0; dt < 4; ++dt)
#pragma unroll
    for (int r = 0; r < 4; ++r) {
      const int srow = c * W1_ + qtile + g * 4 + r;
      ctx[(size_t)(b * S_LEN + srow) * D_MODEL + h * DHE + dt * 16 + l16] = f2bf(acc[dt][r]);
    }
}

extern "C" void kernel_launch(void* const* d_in, const int* in_sizes, int n_in,
                              void* d_out, int out_size, void* d_ws, size_t ws_size,
                              hipStream_t stream) {
  (void)in_sizes; (void)n_in; (void)out_size; (void)ws_size;
  const float* inputs  = (const float*)d_in[0];
  const int*   lengths = (const int*)d_in[1];
  const float* pos_emb = (const float*)d_in[2];
  const float* tok_emb = (const float*)d_in[3];
  const float* ln_emb_g = (const float*)d_in[4];
  const float* ln_emb_b = (const float*)d_in[5];
  const float* Wq = (const float*)d_in[6];
  const float* bq = (const float*)d_in[7];
  const float* Wk = (const float*)d_in[8];
  const float* bk = (const float*)d_in[9];
  const float* Wv = (const float*)d_in[10];
  const float* bv = (const float*)d_in[11];
  const float* Wo = (const float*)d_in[12];
  const float* bo = (const float*)d_in[13];
  const float* ln1_g = (const float*)d_in[14];
  const float* ln1_b = (const float*)d_in[15];
  const float* Wi = (const float*)d_in[16];
  const float* bi = (const float*)d_in[17];
  const float* Wf = (const float*)d_in[18];
  const float* bf2 = (const float*)d_in[19];
  const float* ln2_g = (const float*)d_in[20];
  const float* ln2_b = (const float*)d_in[21];

  const size_t MTOK = (size_t)2 * S_LEN;     // 8192
  const size_t DD  = (size_t)D_MODEL * D_MODEL;
  const size_t DDF = (size_t)D_MODEL * DFF_;

  char* ws = (char*)d_ws;
  size_t off = 0;
  auto alloc = [&](size_t bytes) { void* p = ws + off; off += (bytes + 255) & ~(size_t)255; return p; };

  short* xb    = (short*)alloc(MTOK * D_MODEL * 2);
  short* qkv   = (short*)alloc(MTOK * QKVN * 2);
  short* vtb   = (short*)alloc(MTOK * D_MODEL * 2);
  float* y     = (float*)alloc(MTOK * D_MODEL * 4);
  short* ctxb  = (short*)alloc(MTOK * D_MODEL * 2);
  short* hb    = (short*)alloc(MTOK * DFF_ * 2);
  short* wqkvt = (short*)alloc((size_t)NL * QKVN * D_MODEL * 2);
  short* wot   = (short*)alloc((size_t)NL * DD * 2);
  short* wit   = (short*)alloc((size_t)NL * DDF * 2);
  short* wft   = (short*)alloc((size_t)NL * DDF * 2);
  float* bqkv  = (float*)alloc((size_t)NL * QKVN * 4);
  float* x = (float*)d_out;

  const dim3 tb(32, 8);
  const size_t QL = (size_t)QKVN * D_MODEL;
  transpose_w<<<dim3(24, 24, NL), tb, 0, stream>>>(Wq, wqkvt,            D_MODEL, D_MODEL, DD, QL, 0.125f);
  transpose_w<<<dim3(24, 24, NL), tb, 0, stream>>>(Wk, wqkvt + 768*768,  D_MODEL, D_MODEL, DD, QL, 1.0f);
  transpose_w<<<dim3(24, 24, NL), tb, 0, stream>>>(Wv, wqkvt + 1536*768, D_MODEL, D_MODEL, DD, QL, 1.0f);
  transpose_w<<<dim3(24, 24, NL), tb, 0, stream>>>(Wo, wot, D_MODEL, D_MODEL, DD, DD, 1.0f);
  transpose_w<<<dim3(96, 24, NL), tb, 0, stream>>>(Wi, wit, D_MODEL, DFF_, DDF, DDF, 1.0f);
  transpose_w<<<dim3(24, 96, NL), tb, 0, stream>>>(Wf, wft, DFF_, D_MODEL, DDF, DDF, 1.0f);
  prep_bias<<<dim3(NL, 3), 768, 0, stream>>>(bq, bk, bv, bqkv);

  ln_kernel<0><<<MTOK, 256, 0, stream>>>(inputs, pos_emb, tok_emb, ln_emb_g, ln_emb_b, x, xb);

  for (int l = 0; l < NL; ++l) {
    gemm8p<4, 0><<<dim3(9, 32), 512, 0, stream>>>(xb, wqkvt + (size_t)l * QL, bqkv + (size_t)l * QKVN,
                                                  qkv, (int)MTOK, QKVN, D_MODEL);
    vtrans<<<dim3(64, NHEAD, 2), dim3(64, 8), 0, stream>>>(qkv, vtb);
    att_fused<<<dim3(64, NHEAD), 512, 0, stream>>>(qkv, vtb, lengths, ctxb);
    gemm8p<2, 1><<<dim3(6, 32), 512, 0, stream>>>(ctxb, wot + (size_t)l * DD, bo + l * D_MODEL,
                                                  y, (int)MTOK, D_MODEL, D_MODEL);
    ln_kernel<1><<<MTOK, 256, 0, stream>>>(x, y, nullptr, ln1_g + l * D_MODEL, ln1_b + l * D_MODEL, x, xb);
    gemm8p<4, 2><<<dim3(12, 32), 512, 0, stream>>>(xb, wit + (size_t)l * DDF, bi + l * DFF_,
                                                   hb, (int)MTOK, DFF_, D_MODEL);
    gemm8p<2, 1><<<dim3(6, 32), 512, 0, stream>>>(hb, wft + (size_t)l * DDF, bf2 + l * D_MODEL,
                                                  y, (int)MTOK, D_MODEL, DFF_);
    ln_kernel<1><<<MTOK, 256, 0, stream>>>(x, y, nullptr, ln2_g + l * D_MODEL, ln2_b + l * D_MODEL, x, xb);
  }
}

// Round 4
// 1337.438 us; speedup vs baseline: 1.2519x; 1.0260x over previous
//
#include <hip/hip_runtime.h>
#include <cstdint>

#define S_LEN 4096
#define D_MODEL 768
#define NHEAD 12
#define DHE 64
#define DFF_ 3072
#define NL 4
#define W1_ 128
#define NC_ 32
#define QKVN 2304

typedef __attribute__((ext_vector_type(8))) short v8s;
typedef __attribute__((ext_vector_type(4))) float v4f;

__device__ __forceinline__ short f2bf(float f) {
  union { float f; unsigned u; } x; x.f = f;
  unsigned r = x.u + 0x7fffu + ((x.u >> 16) & 1u);
  return (short)(r >> 16);
}

__device__ __forceinline__ void load_lds16(const short* g, short* l) {
  __builtin_amdgcn_global_load_lds((const __attribute__((address_space(1))) void*)g,
                                   (__attribute__((address_space(3))) void*)l, 16, 0, 0);
}

// phase fence: pin all instruction motion at phase boundaries, then HW barrier
#define PFENCE() do { asm volatile("" ::: "memory"); __builtin_amdgcn_sched_barrier(0); __builtin_amdgcn_s_barrier(); } while (0)

// ---- stage one kh-plane (LDS-linear dest, inverse-swizzled global source) ----
// plane layout: [row][32 bf16], row stride 64B, swizzle: byte ^= ((row>>1)&3)<<4
template<int NISS>
__device__ __forceinline__ void stage_plane(const short* __restrict__ gbase, int ldK,
                                            short* lplane, int tid) {
  const int wid = tid >> 6;
#pragma unroll
  for (int r = 0; r < NISS; ++r) {
    const int o = r * 8192 + tid * 16;                     // physical byte in plane
    const int row = o >> 6;
    const int lb = (o & 63) ^ (((row >> 1) & 3) << 4);     // logical byte within row
    const short* g = (const short*)((const char*)gbase + (size_t)row * (size_t)(ldK * 2) + lb);
    short* l = (short*)((char*)lplane + r * 8192 + wid * 1024);
    load_lds16(g, l);
  }
}

__device__ __forceinline__ v8s ldfrag(const short* plane, int row, int g) {
  const int b = (g << 4) ^ (((row >> 1) & 3) << 4);
  return *(const v8s*)((const char*)plane + row * 64 + b);
}

// ---------------- 8-phase 256xBN GEMM: C = A[M,K] @ Bt[N,K]^T + bias ----------------
// EPI 0: bf16 out.  EPI 1: f32 out.  EPI 2: gelu -> bf16.
template<int NF, int EPI>
__global__ __launch_bounds__(512, 2)
void gemm8p(const short* __restrict__ A, const short* __restrict__ Bt,
            const float* __restrict__ bias, void* __restrict__ outp,
            int M, int N, int K)
{
  constexpr int BN = NF * 64;
  constexpr int AN = 2;                      // A plane = 16KB -> 2 issue rounds
  constexpr int BNI = (BN * 64) / 8192;      // B plane issues: 2 (BN=256) or 1 (BN=128)
  __shared__ short sA[2][2][256 * 32];
  __shared__ short sB[2][2][BN * 32];
  const int tid = threadIdx.x;
  const int lane = tid & 63, wid = tid >> 6;
  const int g = lane >> 4, l16 = lane & 15;
  const int wr = wid >> 2, wc = wid & 3;
  const int nt = K >> 6;

  // XCD-bijective swizzle (m204): physical id p -> logical lb, contiguous per XCD.
  // bn-fastest within the XCD chunk => same-bm blocks co-resident on one XCD L2.
  const int gx = gridDim.x;
  const int nwg = gx * gridDim.y;
  const int p = blockIdx.y * gx + blockIdx.x;
  const int q8 = nwg >> 3, r8 = nwg & 7;
  const int xcd = p & 7, wi = p >> 3;
  const int lb = (xcd < r8 ? xcd * (q8 + 1) : r8 * (q8 + 1) + (xcd - r8) * q8) + wi;
  const int bn_ = lb % gx, bm_ = lb / gx;

  const short* Ab = A + (size_t)(bm_ * 256) * K;
  const short* Bb = Bt + (size_t)(bn_ * BN) * K;

  v4f acc[8][NF] = {};

  // prologue: t0 complete + t1 kh0
  stage_plane<AN >(Ab,      K, &sA[0][0][0], tid);
  stage_plane<BNI>(Bb,      K, &sB[0][0][0], tid);
  stage_plane<AN >(Ab + 32, K, &sA[0][1][0], tid);
  stage_plane<BNI>(Bb + 32, K, &sB[0][1][0], tid);
  stage_plane<AN >(Ab + 64, K, &sA[1][0][0], tid);
  stage_plane<BNI>(Bb + 64, K, &sB[1][0][0], tid);
  if constexpr (NF == 4) asm volatile("s_waitcnt vmcnt(4)");
  else                   asm volatile("s_waitcnt vmcnt(3)");
  __builtin_amdgcn_s_barrier();

  const int arow = wr * 128 + l16;
  const int brow = wc * (NF * 16) + l16;

  for (int t = 0; t < nt; ++t) {
    const int cur = t & 1, nxt = cur ^ 1;
    const short* pA0 = &sA[cur][0][0];
    const short* pA1 = &sA[cur][1][0];
    const short* pB0 = &sB[cur][0][0];
    const short* pB1 = &sB[cur][1][0];
    v8s fa[4], fb[NF];

    // ---- phase a: kk0, m0-3 (+stage t+1 A-kh1 into nxt buf)
#pragma unroll
    for (int m = 0; m < 4; ++m) fa[m] = ldfrag(pA0, arow + m * 16, g);
#pragma unroll
    for (int n = 0; n < NF; ++n) fb[n] = ldfrag(pB0, brow + n * 16, g);
    if (t + 1 < nt) stage_plane<AN>(Ab + (t + 1) * 64 + 32, K, &sA[nxt][1][0], tid);
    PFENCE();
    __builtin_amdgcn_s_setprio(1);
#pragma unroll
    for (int m = 0; m < 4; ++m)
#pragma unroll
      for (int n = 0; n < NF; ++n)
        acc[m][n] = __builtin_amdgcn_mfma_f32_16x16x32_bf16(fa[m], fb[n], acc[m][n], 0, 0, 0);
    __builtin_amdgcn_s_setprio(0);
    PFENCE();

    // ---- phase b: kk0, m4-7 (fb reused; +stage t+1 B-kh1)
#pragma unroll
    for (int m = 0; m < 4; ++m) fa[m] = ldfrag(pA0, arow + 64 + m * 16, g);
    if (t + 1 < nt) stage_plane<BNI>(Bb + (t + 1) * 64 + 32, K, &sB[nxt][1][0], tid);
    PFENCE();
    __builtin_amdgcn_s_setprio(1);
#pragma unroll
    for (int m = 0; m < 4; ++m)
#pragma unroll
      for (int n = 0; n < NF; ++n)
        acc[4 + m][n] = __builtin_amdgcn_mfma_f32_16x16x32_bf16(fa[m], fb[n], acc[4 + m][n], 0, 0, 0);
    __builtin_amdgcn_s_setprio(0);
    PFENCE();

    // ---- phase c: kk1, m0-3 (+stage t+2 A-kh0 into cur buf: region freed after phase b)
#pragma unroll
    for (int m = 0; m < 4; ++m) fa[m] = ldfrag(pA1, arow + m * 16, g);
#pragma unroll
    for (int n = 0; n < NF; ++n) fb[n] = ldfrag(pB1, brow + n * 16, g);
    if (t + 2 < nt) stage_plane<AN>(Ab + (t + 2) * 64, K, &sA[cur][0][0], tid);
    PFENCE();
    __builtin_amdgcn_s_setprio(1);
#pragma unroll
    for (int m = 0; m < 4; ++m)
#pragma unroll
      for (int n = 0; n < NF; ++n)
        acc[m][n] = __builtin_amdgcn_mfma_f32_16x16x32_bf16(fa[m], fb[n], acc[m][n], 0, 0, 0);
    __builtin_amdgcn_s_setprio(0);
    PFENCE();

    // ---- phase d: kk1, m4-7 (+stage t+2 B-kh0; counted vmcnt at tile boundary)
#pragma unroll
    for (int m = 0; m < 4; ++m) fa[m] = ldfrag(pA1, arow + 64 + m * 16, g);
    if (t + 2 < nt) stage_plane<BNI>(Bb + (t + 2) * 64, K, &sB[cur][0][0], tid);
    asm volatile("" ::: "memory");
    __builtin_amdgcn_sched_barrier(0);
    __builtin_amdgcn_s_barrier();
    __builtin_amdgcn_s_setprio(1);
#pragma unroll
    for (int m = 0; m < 4; ++m)
#pragma unroll
      for (int n = 0; n < NF; ++n)
        acc[4 + m][n] = __builtin_amdgcn_mfma_f32_16x16x32_bf16(fa[m], fb[n], acc[4 + m][n], 0, 0, 0);
    __builtin_amdgcn_s_setprio(0);
    asm volatile("" ::: "memory");
    __builtin_amdgcn_sched_barrier(0);
    if (t < nt - 2) {
      if constexpr (NF == 4) asm volatile("s_waitcnt vmcnt(4)");
      else                   asm volatile("s_waitcnt vmcnt(3)");
    } else {
      asm volatile("s_waitcnt vmcnt(0)");
    }
    __builtin_amdgcn_s_barrier();
  }

  // epilogue
  const int row0 = bm_ * 256 + wr * 128;
  const int col0 = bn_ * BN + wc * NF * 16;
#pragma unroll
  for (int m = 0; m < 8; ++m)
#pragma unroll
    for (int n = 0; n < NF; ++n) {
      const int col = col0 + n * 16 + l16;
      const float bc = bias[col];
#pragma unroll
      for (int r = 0; r < 4; ++r) {
        const int row = row0 + m * 16 + g * 4 + r;
        const float v = acc[m][n][r] + bc;
        if (EPI == 0) {
          ((short*)outp)[(size_t)row * N + col] = f2bf(v);
        } else if (EPI == 1) {
          ((float*)outp)[(size_t)row * N + col] = v;
        } else {
          const float e = __expf(1.5957691216057308f * (v + 0.044715f * v * v * v));
          ((short*)outp)[(size_t)row * N + col] = f2bf(v - v / (1.0f + e));
        }
      }
    }
}

// ---------------- weight transpose f32[K,N] -> bf16[N,K] (with scale fold) ----------------
__global__ __launch_bounds__(256)
void transpose_w(const float* __restrict__ in, short* __restrict__ out, int K, int N,
                 size_t in_ls, size_t out_ls, float scale)
{
  __shared__ float t[32][33];
  const int n0 = blockIdx.x * 32, k0 = blockIdx.y * 32;
  const float* src = in + (size_t)blockIdx.z * in_ls;
  short* dst = out + (size_t)blockIdx.z * out_ls;
  const int tx = threadIdx.x, ty = threadIdx.y;   // (32,8)
#pragma unroll
  for (int i = 0; i < 4; ++i)
    t[ty + 8*i][tx] = src[(size_t)(k0 + ty + 8*i) * N + n0 + tx];
  __syncthreads();
#pragma unroll
  for (int i = 0; i < 4; ++i)
    dst[(size_t)(n0 + ty + 8*i) * K + k0 + tx] = f2bf(t[tx][ty + 8*i] * scale);
}

__global__ void prep_bias(const float* __restrict__ bq, const float* __restrict__ bk,
                          const float* __restrict__ bv, float* __restrict__ out)
{
  const int l = blockIdx.x, p = blockIdx.y, c = threadIdx.x;
  const float* s = p == 0 ? bq : (p == 1 ? bk : bv);
  out[(l * 3 + p) * 768 + c] = s[l * 768 + c] * (p == 0 ? 0.125f : 1.0f);
}

// ---------------- V transpose: qkv[B,S,2304] v-part -> vt [B,H,DH,S] ----------------
__global__ __launch_bounds__(512)
void vtrans(const short* __restrict__ qkv, short* __restrict__ vt)
{
  __shared__ short t[64][65];
  const int s0 = blockIdx.x * 64, h = blockIdx.y, b = blockIdx.z;
  const int tx = threadIdx.x, ty = threadIdx.y;   // (64,8)
#pragma unroll
  for (int i = 0; i < 8; ++i)
    t[ty + 8*i][tx] = qkv[(size_t)(b * S_LEN + s0 + ty + 8*i) * QKVN + 1536 + h * DHE + tx];
  __syncthreads();
#pragma unroll
  for (int i = 0; i < 8; ++i)
    vt[((size_t)(b * NHEAD + h) * DHE + ty + 8*i) * S_LEN + s0 + tx] = t[tx][ty + 8*i];
}

// ---------------- LayerNorm. MODE 0: embed (in0 + pos + tok), MODE 1: residual ----------------
template<int MODE>
__global__ __launch_bounds__(256)
void ln_kernel(const float* __restrict__ in0, const float* __restrict__ in1,
               const float* __restrict__ in2,
               const float* __restrict__ gamma, const float* __restrict__ beta,
               float* __restrict__ outf, short* __restrict__ outb)
{
  __shared__ float red[8];
  const int row = blockIdx.x;
  const int tid = threadIdx.x;
  const int wave = tid >> 6, lane = tid & 63;
  float v[3];
#pragma unroll
  for (int i = 0; i < 3; ++i) {
    const int c = tid + i * 256;
    const size_t idx = (size_t)row * D_MODEL + c;
    if (MODE == 0) {
      const int s = row & (S_LEN - 1);
      v[i] = in0[idx] + in1[(size_t)(2 + s) * D_MODEL + c] + in2[c];
    } else {
      v[i] = in0[idx] + in1[idx];
    }
  }
  float sum = v[0] + v[1] + v[2];
#pragma unroll
  for (int m = 1; m < 64; m <<= 1) sum += __shfl_xor(sum, m, 64);
  if (lane == 0) red[wave] = sum;
  __syncthreads();
  const float mean = (red[0] + red[1] + red[2] + red[3]) * (1.0f / 768.0f);
  float sq = 0.f;
#pragma unroll
  for (int i = 0; i < 3; ++i) { float d = v[i] - mean; sq += d * d; }
#pragma unroll
  for (int m = 1; m < 64; m <<= 1) sq += __shfl_xor(sq, m, 64);
  if (lane == 0) red[4 + wave] = sq;
  __syncthreads();
  const float var = (red[4] + red[5] + red[6] + red[7]) * (1.0f / 768.0f);
  const float rstd = 1.0f / sqrtf(var + 1e-12f);
#pragma unroll
  for (int i = 0; i < 3; ++i) {
    const int c = tid + i * 256;
    const size_t idx = (size_t)row * D_MODEL + c;
    const float o = (v[i] - mean) * rstd * gamma[c] + beta[c];
    outf[idx] = o;
    outb[idx] = f2bf(o);
  }
}

// ---------------- fused attention v2: barrier-free, wave-private P ----------------
// grid (128 = b*64 + c*2 + hq, NHEAD), 256 threads (4 waves x 16 q-rows = 64 rows).
// P per-wave LDS region [16][392] bf16 (padded stride 784B: bank off = 4*row mod 32,
// 2-way conflicts = free). Total 49KB -> 3 blocks/CU, 12 waves/CU, NO __syncthreads.
__global__ __launch_bounds__(256, 3)
void att_fused(const short* __restrict__ qkv, const short* __restrict__ vt,
               const int* __restrict__ lengths, short* __restrict__ ctx)
{
  __shared__ __align__(16) short Pl[4 * 16 * 392];
  const int b = blockIdx.x >> 6, c = (blockIdx.x >> 1) & 31, hq = blockIdx.x & 1;
  const int h = blockIdx.y;
  const int len = lengths[b];
  const int wave = threadIdx.x >> 6, lane = threadIdx.x & 63;
  const int g = lane >> 4, l16 = lane & 15;
  const int qtile = hq * 64 + wave * 16;          // q-row tile within the 128-chunk
  short* Pw = &Pl[wave * 16 * 392];               // this wave's private P region

  // ---- QK^T for 16 q-rows of this wave
  const short* qp = qkv + (size_t)(b * S_LEN + c * W1_ + qtile + l16) * QKVN + h * DHE;
  const v8s a0 = *(const v8s*)(qp + g * 8);
  const v8s a1 = *(const v8s*)(qp + 32 + g * 8);
  v4f s[24];
#pragma unroll
  for (int nt = 0; nt < 24; ++nt) {
    const int jg = c * W1_ - W1_ + nt * 16 + l16;
    const int jc = jg < 0 ? 0 : (jg > S_LEN - 1 ? S_LEN - 1 : jg);
    const short* kp = qkv + (size_t)(b * S_LEN + jc) * QKVN + 768 + h * DHE;
    v4f t = {0.f, 0.f, 0.f, 0.f};
    t = __builtin_amdgcn_mfma_f32_16x16x32_bf16(a0, *(const v8s*)(kp + g * 8), t, 0, 0, 0);
    t = __builtin_amdgcn_mfma_f32_16x16x32_bf16(a1, *(const v8s*)(kp + 32 + g * 8), t, 0, 0, 0);
    s[nt] = t;
  }
  // ---- mask + softmax (row reduce within 16-lane group) + write P to own LDS region
#pragma unroll
  for (int r = 0; r < 4; ++r) {
    const int qpos = qtile + g * 4 + r;           // row within the 128-chunk
    float m = -3.0e38f;
#pragma unroll
    for (int nt = 0; nt < 24; ++nt) {
      const int j = nt * 16 + l16;
      const int jg = c * W1_ - W1_ + j;
      const bool ok = (j >= qpos) & (j <= qpos + 2 * W1_) & (jg >= 0) & (jg < len);
      const float v = ok ? s[nt][r] : -1e9f;
      s[nt][r] = v;
      m = fmaxf(m, v);
    }
#pragma unroll
    for (int d = 1; d < 16; d <<= 1) m = fmaxf(m, __shfl_xor(m, d, 64));
    float su = 0.f;
#pragma unroll
    for (int nt = 0; nt < 24; ++nt) {
      const float e = __expf(s[nt][r] - m);
      s[nt][r] = e;
      su += e;
    }
#pragma unroll
    for (int d = 1; d < 16; d <<= 1) su += __shfl_xor(su, d, 64);
    const float f = (c * W1_ + qpos < len) ? 1.0f / su : 0.0f;
    short* prow = Pw + (g * 4 + r) * 392;         // local row = qpos - qtile
#pragma unroll
    for (int nt = 0; nt < 24; ++nt)
      prow[nt * 16 + l16] = f2bf(s[nt][r] * f);
  }
  // wave-private region: no __syncthreads needed; drain own LDS writes only
  asm volatile("s_waitcnt lgkmcnt(0)" ::: "memory");
  __builtin_amdgcn_sched_barrier(0);

  // ---- PV: this wave's 16 q-rows x 64 d, K=384
  v4f acc[4] = {};
  const short* vtb = vt + (size_t)(b * NHEAD + h) * DHE * S_LEN;
#pragma unroll
  for (int kc = 0; kc < 12; ++kc) {
    const v8s fa = *(const v8s*)&Pw[l16 * 392 + kc * 32 + g * 8];
    const int jg = c * W1_ - W1_ + kc * 32 + g * 8;
    const int jc = jg < 0 ? 0 : (jg > S_LEN - 8 ? S_LEN - 8 : jg);
#pragma unroll
    for (int dt = 0; dt < 4; ++dt) {
      const v8s fb = *(const v8s*)&vtb[(size_t)(dt * 16 + l16) * S_LEN + jc];
      acc[dt] = __builtin_amdgcn_mfma_f32_16x16x32_bf16(fa, fb, acc[dt], 0, 0, 0);
    }
  }
#pragma unroll
  for (int dt = 0; dt < 4; ++dt)
#pragma unroll
    for (int r = 0; r < 4; ++r) {
      const int srow = c * W1_ + qtile + g * 4 + r;
      ctx[(size_t)(b * S_LEN + srow) * D_MODEL + h * DHE + dt * 16 + l16] = f2bf(acc[dt][r]);
    }
}

extern "C" void kernel_launch(void* const* d_in, const int* in_sizes, int n_in,
                              void* d_out, int out_size, void* d_ws, size_t ws_size,
                              hipStream_t stream) {
  (void)in_sizes; (void)n_in; (void)out_size; (void)ws_size;
  const float* inputs  = (const float*)d_in[0];
  const int*   lengths = (const int*)d_in[1];
  const float* pos_emb = (const float*)d_in[2];
  const float* tok_emb = (const float*)d_in[3];
  const float* ln_emb_g = (const float*)d_in[4];
  const float* ln_emb_b = (const float*)d_in[5];
  const float* Wq = (const float*)d_in[6];
  const float* bq = (const float*)d_in[7];
  const float* Wk = (const float*)d_in[8];
  const float* bk = (const float*)d_in[9];
  const float* Wv = (const float*)d_in[10];
  const float* bv = (const float*)d_in[11];
  const float* Wo = (const float*)d_in[12];
  const float* bo = (const float*)d_in[13];
  const float* ln1_g = (const float*)d_in[14];
  const float* ln1_b = (const float*)d_in[15];
  const float* Wi = (const float*)d_in[16];
  const float* bi = (const float*)d_in[17];
  const float* Wf = (const float*)d_in[18];
  const float* bf2 = (const float*)d_in[19];
  const float* ln2_g = (const float*)d_in[20];
  const float* ln2_b = (const float*)d_in[21];

  const size_t MTOK = (size_t)2 * S_LEN;     // 8192
  const size_t DD  = (size_t)D_MODEL * D_MODEL;
  const size_t DDF = (size_t)D_MODEL * DFF_;

  char* ws = (char*)d_ws;
  size_t off = 0;
  auto alloc = [&](size_t bytes) { void* p = ws + off; off += (bytes + 255) & ~(size_t)255; return p; };

  short* xb    = (short*)alloc(MTOK * D_MODEL * 2);
  short* qkv   = (short*)alloc(MTOK * QKVN * 2);
  short* vtb   = (short*)alloc(MTOK * D_MODEL * 2);
  float* y     = (float*)alloc(MTOK * D_MODEL * 4);
  short* ctxb  = (short*)alloc(MTOK * D_MODEL * 2);
  short* hb    = (short*)alloc(MTOK * DFF_ * 2);
  short* wqkvt = (short*)alloc((size_t)NL * QKVN * D_MODEL * 2);
  short* wot   = (short*)alloc((size_t)NL * DD * 2);
  short* wit   = (short*)alloc((size_t)NL * DDF * 2);
  short* wft   = (short*)alloc((size_t)NL * DDF * 2);
  float* bqkv  = (float*)alloc((size_t)NL * QKVN * 4);
  float* x = (float*)d_out;

  const dim3 tb(32, 8);
  const size_t QL = (size_t)QKVN * D_MODEL;
  transpose_w<<<dim3(24, 24, NL), tb, 0, stream>>>(Wq, wqkvt,            D_MODEL, D_MODEL, DD, QL, 0.125f);
  transpose_w<<<dim3(24, 24, NL), tb, 0, stream>>>(Wk, wqkvt + 768*768,  D_MODEL, D_MODEL, DD, QL, 1.0f);
  transpose_w<<<dim3(24, 24, NL), tb, 0, stream>>>(Wv, wqkvt + 1536*768, D_MODEL, D_MODEL, DD, QL, 1.0f);
  transpose_w<<<dim3(24, 24, NL), tb, 0, stream>>>(Wo, wot, D_MODEL, D_MODEL, DD, DD, 1.0f);
  transpose_w<<<dim3(96, 24, NL), tb, 0, stream>>>(Wi, wit, D_MODEL, DFF_, DDF, DDF, 1.0f);
  transpose_w<<<dim3(24, 96, NL), tb, 0, stream>>>(Wf, wft, DFF_, D_MODEL, DDF, DDF, 1.0f);
  prep_bias<<<dim3(NL, 3), 768, 0, stream>>>(bq, bk, bv, bqkv);

  ln_kernel<0><<<MTOK, 256, 0, stream>>>(inputs, pos_emb, tok_emb, ln_emb_g, ln_emb_b, x, xb);

  for (int l = 0; l < NL; ++l) {
    gemm8p<4, 0><<<dim3(9, 32), 512, 0, stream>>>(xb, wqkvt + (size_t)l * QL, bqkv + (size_t)l * QKVN,
                                                  qkv, (int)MTOK, QKVN, D_MODEL);
    vtrans<<<dim3(64, NHEAD, 2), dim3(64, 8), 0, stream>>>(qkv, vtb);
    att_fused<<<dim3(128, NHEAD), 256, 0, stream>>>(qkv, vtb, lengths, ctxb);
    gemm8p<2, 1><<<dim3(6, 32), 512, 0, stream>>>(ctxb, wot + (size_t)l * DD, bo + l * D_MODEL,
                                                  y, (int)MTOK, D_MODEL, D_MODEL);
    ln_kernel<1><<<MTOK, 256, 0, stream>>>(x, y, nullptr, ln1_g + l * D_MODEL, ln1_b + l * D_MODEL, x, xb);
    gemm8p<4, 2><<<dim3(12, 32), 512, 0, stream>>>(xb, wit + (size_t)l * DDF, bi + l * DFF_,
                                                   hb, (int)MTOK, DFF_, D_MODEL);
    gemm8p<2, 1><<<dim3(6, 32), 512, 0, stream>>>(hb, wft + (size_t)l * DDF, bf2 + l * D_MODEL,
                                                  y, (int)MTOK, D_MODEL, DFF_);
    ln_kernel<1><<<MTOK, 256, 0, stream>>>(x, y, nullptr, ln2_g + l * D_MODEL, ln2_b + l * D_MODEL, x, xb);
  }
}

// Round 5
// 1297.787 us; speedup vs baseline: 1.2901x; 1.0306x over previous
//
#include <hip/hip_runtime.h>
#include <cstdint>

#define S_LEN 4096
#define D_MODEL 768
#define NHEAD 12
#define DHE 64
#define DFF_ 3072
#define NL 4
#define W1_ 128
#define NC_ 32
#define QKVN 2304

typedef __attribute__((ext_vector_type(8))) short v8s;
typedef __attribute__((ext_vector_type(4))) float v4f;

__device__ __forceinline__ short f2bf(float f) {
  union { float f; unsigned u; } x; x.f = f;
  unsigned r = x.u + 0x7fffu + ((x.u >> 16) & 1u);
  return (short)(r >> 16);
}

__device__ __forceinline__ void load_lds16(const short* g, short* l) {
  __builtin_amdgcn_global_load_lds((const __attribute__((address_space(1))) void*)g,
                                   (__attribute__((address_space(3))) void*)l, 16, 0, 0);
}

// phase fence: pin all instruction motion at phase boundaries, then HW barrier
#define PFENCE() do { asm volatile("" ::: "memory"); __builtin_amdgcn_sched_barrier(0); __builtin_amdgcn_s_barrier(); } while (0)

// ---- stage one kh-plane (LDS-linear dest, inverse-swizzled global source) ----
// plane layout: [row][32 bf16], row stride 64B, swizzle: byte ^= ((row>>1)&3)<<4
template<int NISS>
__device__ __forceinline__ void stage_plane(const short* __restrict__ gbase, int ldK,
                                            short* lplane, int tid) {
  const int wid = tid >> 6;
#pragma unroll
  for (int r = 0; r < NISS; ++r) {
    const int o = r * 8192 + tid * 16;                     // physical byte in plane
    const int row = o >> 6;
    const int lb = (o & 63) ^ (((row >> 1) & 3) << 4);     // logical byte within row
    const short* g = (const short*)((const char*)gbase + (size_t)row * (size_t)(ldK * 2) + lb);
    short* l = (short*)((char*)lplane + r * 8192 + wid * 1024);
    load_lds16(g, l);
  }
}

__device__ __forceinline__ v8s ldfrag(const short* plane, int row, int g) {
  const int b = (g << 4) ^ (((row >> 1) & 3) << 4);
  return *(const v8s*)((const char*)plane + row * 64 + b);
}

// ---------------- 8-phase 256xBN GEMM: C = A[M,K] @ Bt[N,K]^T + bias ----------------
// EPI 0: bf16 out.  EPI 1: f32 out.  EPI 2: gelu -> bf16.
template<int NF, int EPI>
__global__ __launch_bounds__(512, 2)
void gemm8p(const short* __restrict__ A, const short* __restrict__ Bt,
            const float* __restrict__ bias, void* __restrict__ outp,
            int M, int N, int K)
{
  constexpr int BN = NF * 64;
  constexpr int AN = 2;                      // A plane = 16KB -> 2 issue rounds
  constexpr int BNI = (BN * 64) / 8192;      // B plane issues: 2 (BN=256) or 1 (BN=128)
  __shared__ short sA[2][2][256 * 32];
  __shared__ short sB[2][2][BN * 32];
  const int tid = threadIdx.x;
  const int lane = tid & 63, wid = tid >> 6;
  const int g = lane >> 4, l16 = lane & 15;
  const int wr = wid >> 2, wc = wid & 3;
  const int nt = K >> 6;

  // XCD-bijective swizzle (m204): physical id p -> logical lb, contiguous per XCD.
  const int gx = gridDim.x;
  const int nwg = gx * gridDim.y;
  const int p = blockIdx.y * gx + blockIdx.x;
  const int q8 = nwg >> 3, r8 = nwg & 7;
  const int xcd = p & 7, wi = p >> 3;
  const int lb = (xcd < r8 ? xcd * (q8 + 1) : r8 * (q8 + 1) + (xcd - r8) * q8) + wi;
  const int bn_ = lb % gx, bm_ = lb / gx;

  const short* Ab = A + (size_t)(bm_ * 256) * K;
  const short* Bb = Bt + (size_t)(bn_ * BN) * K;

  v4f acc[8][NF] = {};

  // prologue: t0 complete + t1 kh0
  stage_plane<AN >(Ab,      K, &sA[0][0][0], tid);
  stage_plane<BNI>(Bb,      K, &sB[0][0][0], tid);
  stage_plane<AN >(Ab + 32, K, &sA[0][1][0], tid);
  stage_plane<BNI>(Bb + 32, K, &sB[0][1][0], tid);
  stage_plane<AN >(Ab + 64, K, &sA[1][0][0], tid);
  stage_plane<BNI>(Bb + 64, K, &sB[1][0][0], tid);
  if constexpr (NF == 4) asm volatile("s_waitcnt vmcnt(4)");
  else                   asm volatile("s_waitcnt vmcnt(3)");
  __builtin_amdgcn_s_barrier();

  const int arow = wr * 128 + l16;
  const int brow = wc * (NF * 16) + l16;

  for (int t = 0; t < nt; ++t) {
    const int cur = t & 1, nxt = cur ^ 1;
    const short* pA0 = &sA[cur][0][0];
    const short* pA1 = &sA[cur][1][0];
    const short* pB0 = &sB[cur][0][0];
    const short* pB1 = &sB[cur][1][0];
    v8s fa[4], fb[NF];

    // ---- phase a: kk0, m0-3 (+stage t+1 A-kh1 into nxt buf)
#pragma unroll
    for (int m = 0; m < 4; ++m) fa[m] = ldfrag(pA0, arow + m * 16, g);
#pragma unroll
    for (int n = 0; n < NF; ++n) fb[n] = ldfrag(pB0, brow + n * 16, g);
    if (t + 1 < nt) stage_plane<AN>(Ab + (t + 1) * 64 + 32, K, &sA[nxt][1][0], tid);
    PFENCE();
    __builtin_amdgcn_s_setprio(1);
#pragma unroll
    for (int m = 0; m < 4; ++m)
#pragma unroll
      for (int n = 0; n < NF; ++n)
        acc[m][n] = __builtin_amdgcn_mfma_f32_16x16x32_bf16(fa[m], fb[n], acc[m][n], 0, 0, 0);
    __builtin_amdgcn_s_setprio(0);
    PFENCE();

    // ---- phase b: kk0, m4-7 (fb reused; +stage t+1 B-kh1)
#pragma unroll
    for (int m = 0; m < 4; ++m) fa[m] = ldfrag(pA0, arow + 64 + m * 16, g);
    if (t + 1 < nt) stage_plane<BNI>(Bb + (t + 1) * 64 + 32, K, &sB[nxt][1][0], tid);
    PFENCE();
    __builtin_amdgcn_s_setprio(1);
#pragma unroll
    for (int m = 0; m < 4; ++m)
#pragma unroll
      for (int n = 0; n < NF; ++n)
        acc[4 + m][n] = __builtin_amdgcn_mfma_f32_16x16x32_bf16(fa[m], fb[n], acc[4 + m][n], 0, 0, 0);
    __builtin_amdgcn_s_setprio(0);
    PFENCE();

    // ---- phase c: kk1, m0-3 (+stage t+2 A-kh0 into cur buf)
#pragma unroll
    for (int m = 0; m < 4; ++m) fa[m] = ldfrag(pA1, arow + m * 16, g);
#pragma unroll
    for (int n = 0; n < NF; ++n) fb[n] = ldfrag(pB1, brow + n * 16, g);
    if (t + 2 < nt) stage_plane<AN>(Ab + (t + 2) * 64, K, &sA[cur][0][0], tid);
    PFENCE();
    __builtin_amdgcn_s_setprio(1);
#pragma unroll
    for (int m = 0; m < 4; ++m)
#pragma unroll
      for (int n = 0; n < NF; ++n)
        acc[m][n] = __builtin_amdgcn_mfma_f32_16x16x32_bf16(fa[m], fb[n], acc[m][n], 0, 0, 0);
    __builtin_amdgcn_s_setprio(0);
    PFENCE();

    // ---- phase d: kk1, m4-7 (+stage t+2 B-kh0; counted vmcnt at tile boundary)
#pragma unroll
    for (int m = 0; m < 4; ++m) fa[m] = ldfrag(pA1, arow + 64 + m * 16, g);
    if (t + 2 < nt) stage_plane<BNI>(Bb + (t + 2) * 64, K, &sB[cur][0][0], tid);
    asm volatile("" ::: "memory");
    __builtin_amdgcn_sched_barrier(0);
    __builtin_amdgcn_s_barrier();
    __builtin_amdgcn_s_setprio(1);
#pragma unroll
    for (int m = 0; m < 4; ++m)
#pragma unroll
      for (int n = 0; n < NF; ++n)
        acc[4 + m][n] = __builtin_amdgcn_mfma_f32_16x16x32_bf16(fa[m], fb[n], acc[4 + m][n], 0, 0, 0);
    __builtin_amdgcn_s_setprio(0);
    asm volatile("" ::: "memory");
    __builtin_amdgcn_sched_barrier(0);
    if (t < nt - 2) {
      if constexpr (NF == 4) asm volatile("s_waitcnt vmcnt(4)");
      else                   asm volatile("s_waitcnt vmcnt(3)");
    } else {
      asm volatile("s_waitcnt vmcnt(0)");
    }
    __builtin_amdgcn_s_barrier();
  }

  // epilogue
  const int row0 = bm_ * 256 + wr * 128;
  const int col0 = bn_ * BN + wc * NF * 16;
#pragma unroll
  for (int m = 0; m < 8; ++m)
#pragma unroll
    for (int n = 0; n < NF; ++n) {
      const int col = col0 + n * 16 + l16;
      const float bc = bias[col];
#pragma unroll
      for (int r = 0; r < 4; ++r) {
        const int row = row0 + m * 16 + g * 4 + r;
        const float v = acc[m][n][r] + bc;
        if (EPI == 0) {
          ((short*)outp)[(size_t)row * N + col] = f2bf(v);
        } else if (EPI == 1) {
          ((float*)outp)[(size_t)row * N + col] = v;
        } else {
          const float e = __expf(1.5957691216057308f * (v + 0.044715f * v * v * v));
          ((short*)outp)[(size_t)row * N + col] = f2bf(v - v / (1.0f + e));
        }
      }
    }
}

// ---------------- weight transpose f32[K,N] -> bf16[N,K] (with scale fold) ----------------
__global__ __launch_bounds__(256)
void transpose_w(const float* __restrict__ in, short* __restrict__ out, int K, int N,
                 size_t in_ls, size_t out_ls, float scale)
{
  __shared__ float t[32][33];
  const int n0 = blockIdx.x * 32, k0 = blockIdx.y * 32;
  const float* src = in + (size_t)blockIdx.z * in_ls;
  short* dst = out + (size_t)blockIdx.z * out_ls;
  const int tx = threadIdx.x, ty = threadIdx.y;   // (32,8)
#pragma unroll
  for (int i = 0; i < 4; ++i)
    t[ty + 8*i][tx] = src[(size_t)(k0 + ty + 8*i) * N + n0 + tx];
  __syncthreads();
#pragma unroll
  for (int i = 0; i < 4; ++i)
    dst[(size_t)(n0 + ty + 8*i) * K + k0 + tx] = f2bf(t[tx][ty + 8*i] * scale);
}

__global__ void prep_bias(const float* __restrict__ bq, const float* __restrict__ bk,
                          const float* __restrict__ bv, float* __restrict__ out)
{
  const int l = blockIdx.x, p = blockIdx.y, c = threadIdx.x;
  const float* s = p == 0 ? bq : (p == 1 ? bk : bv);
  out[(l * 3 + p) * 768 + c] = s[l * 768 + c] * (p == 0 ? 0.125f : 1.0f);
}

// ---------------- V transpose: qkv[B,S,2304] v-part -> vt [B,H,DH,S] ----------------
__global__ __launch_bounds__(512)
void vtrans(const short* __restrict__ qkv, short* __restrict__ vt)
{
  __shared__ short t[64][65];
  const int s0 = blockIdx.x * 64, h = blockIdx.y, b = blockIdx.z;
  const int tx = threadIdx.x, ty = threadIdx.y;   // (64,8)
#pragma unroll
  for (int i = 0; i < 8; ++i)
    t[ty + 8*i][tx] = qkv[(size_t)(b * S_LEN + s0 + ty + 8*i) * QKVN + 1536 + h * DHE + tx];
  __syncthreads();
#pragma unroll
  for (int i = 0; i < 8; ++i)
    vt[((size_t)(b * NHEAD + h) * DHE + ty + 8*i) * S_LEN + s0 + tx] = t[tx][ty + 8*i];
}

// ---------------- LayerNorm. MODE 0: embed (in0 + pos + tok), MODE 1: residual ----------------
template<int MODE>
__global__ __launch_bounds__(256)
void ln_kernel(const float* __restrict__ in0, const float* __restrict__ in1,
               const float* __restrict__ in2,
               const float* __restrict__ gamma, const float* __restrict__ beta,
               float* __restrict__ outf, short* __restrict__ outb)
{
  __shared__ float red[8];
  const int row = blockIdx.x;
  const int tid = threadIdx.x;
  const int wave = tid >> 6, lane = tid & 63;
  float v[3];
#pragma unroll
  for (int i = 0; i < 3; ++i) {
    const int c = tid + i * 256;
    const size_t idx = (size_t)row * D_MODEL + c;
    if (MODE == 0) {
      const int s = row & (S_LEN - 1);
      v[i] = in0[idx] + in1[(size_t)(2 + s) * D_MODEL + c] + in2[c];
    } else {
      v[i] = in0[idx] + in1[idx];
    }
  }
  float sum = v[0] + v[1] + v[2];
#pragma unroll
  for (int m = 1; m < 64; m <<= 1) sum += __shfl_xor(sum, m, 64);
  if (lane == 0) red[wave] = sum;
  __syncthreads();
  const float mean = (red[0] + red[1] + red[2] + red[3]) * (1.0f / 768.0f);
  float sq = 0.f;
#pragma unroll
  for (int i = 0; i < 3; ++i) { float d = v[i] - mean; sq += d * d; }
#pragma unroll
  for (int m = 1; m < 64; m <<= 1) sq += __shfl_xor(sq, m, 64);
  if (lane == 0) red[4 + wave] = sq;
  __syncthreads();
  const float var = (red[4] + red[5] + red[6] + red[7]) * (1.0f / 768.0f);
  const float rstd = 1.0f / sqrtf(var + 1e-12f);
#pragma unroll
  for (int i = 0; i < 3; ++i) {
    const int c = tid + i * 256;
    const size_t idx = (size_t)row * D_MODEL + c;
    const float o = (v[i] - mean) * rstd * gamma[c] + beta[c];
    outf[idx] = o;
    outb[idx] = f2bf(o);
  }
}

// ---------------- fused attention v3: batched-pipelined gathers, wave-private P ----------------
// grid 1536 blocks x 256 thr (4 waves x 16 q-rows). XCD swizzle: each XCD owns 3 (b,h)
// combos x all (c,hq) so consecutive c reuse the K/V window in its private L2.
// K loads: 12 batches of 4 (double-buffered kf) consumed under s_waitcnt vmcnt(4)
// (vmcnt waits oldest-first => newest-4 in flight = next batch). Same for V in PV.
__global__ __launch_bounds__(256, 2)
void att_fused(const short* __restrict__ qkv, const short* __restrict__ vt,
               const int* __restrict__ lengths, short* __restrict__ ctx)
{
  __shared__ __align__(16) short Pl[4 * 16 * 392];
  // XCD swizzle decode: 1536 blocks = 8 XCD x 192; lb = ((b*12+h)*32 + c)*2 + hq
  const int p = blockIdx.x;
  const int lb = (p & 7) * 192 + (p >> 3);
  const int hq = lb & 1, c = (lb >> 1) & 31, bh = lb >> 6;
  const int b = bh / 12, h = bh - b * 12;
  const int len = lengths[b];
  const int wave = threadIdx.x >> 6, lane = threadIdx.x & 63;
  const int g = lane >> 4, l16 = lane & 15;
  const int qtile = hq * 64 + wave * 16;          // q-row tile within the 128-chunk
  short* Pw = &Pl[wave * 16 * 392];               // this wave's private P region

  // ---- Q fragments (oldest VMEM; covered by any later counted vmcnt)
  const short* qp = qkv + (size_t)(b * S_LEN + c * W1_ + qtile + l16) * QKVN + h * DHE;
  const v8s a0 = *(const v8s*)(qp + g * 8);
  const v8s a1 = *(const v8s*)(qp + 32 + g * 8);

  const short* kbase = qkv + 768 + h * DHE;
  const short* vtb = vt + (size_t)(b * NHEAD + h) * DHE * S_LEN;
  const int j0 = c * W1_ - W1_;

  // ---- QK^T: 12 batches of 4 loads (2 nt x 2 halves), double-buffered
  v4f s[24];
  v8s kf[2][4];
#pragma unroll
  for (int u = 0; u < 2; ++u) {
    const int jg = j0 + u * 16 + l16;
    const int jc = jg < 0 ? 0 : (jg > S_LEN - 1 ? S_LEN - 1 : jg);
    const short* kp = kbase + (size_t)(b * S_LEN + jc) * QKVN;
    kf[0][2 * u]     = *(const v8s*)(kp + g * 8);
    kf[0][2 * u + 1] = *(const v8s*)(kp + 32 + g * 8);
  }
#pragma unroll
  for (int i = 0; i < 12; ++i) {
    if (i < 11) {
#pragma unroll
      for (int u = 0; u < 2; ++u) {
        const int jg = j0 + (2 * (i + 1) + u) * 16 + l16;
        const int jc = jg < 0 ? 0 : (jg > S_LEN - 1 ? S_LEN - 1 : jg);
        const short* kp = kbase + (size_t)(b * S_LEN + jc) * QKVN;
        kf[(i + 1) & 1][2 * u]     = *(const v8s*)(kp + g * 8);
        kf[(i + 1) & 1][2 * u + 1] = *(const v8s*)(kp + 32 + g * 8);
      }
    }
    __builtin_amdgcn_sched_barrier(0);
    if (i < 11) asm volatile("s_waitcnt vmcnt(4)" ::: "memory");
    else        asm volatile("s_waitcnt vmcnt(0)" ::: "memory");
    __builtin_amdgcn_sched_barrier(0);
#pragma unroll
    for (int u = 0; u < 2; ++u) {
      v4f t = {0.f, 0.f, 0.f, 0.f};
      t = __builtin_amdgcn_mfma_f32_16x16x32_bf16(a0, kf[i & 1][2 * u], t, 0, 0, 0);
      t = __builtin_amdgcn_mfma_f32_16x16x32_bf16(a1, kf[i & 1][2 * u + 1], t, 0, 0, 0);
      s[2 * i + u] = t;
    }
  }

  // ---- prefetch V batch 0 (kc=0, dt 0..3); latency hides under softmax
  v8s vf[2][4];
  {
    const int jg = j0 + g * 8;
    const int jc = jg < 0 ? 0 : (jg > S_LEN - 8 ? S_LEN - 8 : jg);
#pragma unroll
    for (int dt = 0; dt < 4; ++dt)
      vf[0][dt] = *(const v8s*)&vtb[(size_t)(dt * 16 + l16) * S_LEN + jc];
  }

  // ---- mask + softmax (row reduce within 16-lane group) + write P to own LDS region
#pragma unroll
  for (int r = 0; r < 4; ++r) {
    const int qpos = qtile + g * 4 + r;           // row within the 128-chunk
    float m = -3.0e38f;
#pragma unroll
    for (int nt = 0; nt < 24; ++nt) {
      const int j = nt * 16 + l16;
      const int jg = j0 + j;
      const bool ok = (j >= qpos) & (j <= qpos + 2 * W1_) & (jg >= 0) & (jg < len);
      const float v = ok ? s[nt][r] : -1e9f;
      s[nt][r] = v;
      m = fmaxf(m, v);
    }
#pragma unroll
    for (int d = 1; d < 16; d <<= 1) m = fmaxf(m, __shfl_xor(m, d, 64));
    float su = 0.f;
#pragma unroll
    for (int nt = 0; nt < 24; ++nt) {
      const float e = __expf(s[nt][r] - m);
      s[nt][r] = e;
      su += e;
    }
#pragma unroll
    for (int d = 1; d < 16; d <<= 1) su += __shfl_xor(su, d, 64);
    const float f = (c * W1_ + qpos < len) ? 1.0f / su : 0.0f;
    short* prow = Pw + (g * 4 + r) * 392;         // local row = qpos - qtile
#pragma unroll
    for (int nt = 0; nt < 24; ++nt)
      prow[nt * 16 + l16] = f2bf(s[nt][r] * f);
  }
  // wave-private region: drain own LDS writes only (no block barrier)
  asm volatile("s_waitcnt lgkmcnt(0)" ::: "memory");
  __builtin_amdgcn_sched_barrier(0);

  // ---- PV: 12 batches of 4 V loads (1 kc x 4 dt), double-buffered
  v4f acc[4] = {};
#pragma unroll
  for (int i = 0; i < 12; ++i) {
    if (i < 11) {
      const int jg = j0 + (i + 1) * 32 + g * 8;
      const int jc = jg < 0 ? 0 : (jg > S_LEN - 8 ? S_LEN - 8 : jg);
#pragma unroll
      for (int dt = 0; dt < 4; ++dt)
        vf[(i + 1) & 1][dt] = *(const v8s*)&vtb[(size_t)(dt * 16 + l16) * S_LEN + jc];
    }
    __builtin_amdgcn_sched_barrier(0);
    if (i < 11) asm volatile("s_waitcnt vmcnt(4)" ::: "memory");
    else        asm volatile("s_waitcnt vmcnt(0)" ::: "memory");
    __builtin_amdgcn_sched_barrier(0);
    const v8s fa = *(const v8s*)&Pw[l16 * 392 + i * 32 + g * 8];
#pragma unroll
    for (int dt = 0; dt < 4; ++dt)
      acc[dt] = __builtin_amdgcn_mfma_f32_16x16x32_bf16(fa, vf[i & 1][dt], acc[dt], 0, 0, 0);
  }
#pragma unroll
  for (int dt = 0; dt < 4; ++dt)
#pragma unroll
    for (int r = 0; r < 4; ++r) {
      const int srow = c * W1_ + qtile + g * 4 + r;
      ctx[(size_t)(b * S_LEN + srow) * D_MODEL + h * DHE + dt * 16 + l16] = f2bf(acc[dt][r]);
    }
}

extern "C" void kernel_launch(void* const* d_in, const int* in_sizes, int n_in,
                              void* d_out, int out_size, void* d_ws, size_t ws_size,
                              hipStream_t stream) {
  (void)in_sizes; (void)n_in; (void)out_size; (void)ws_size;
  const float* inputs  = (const float*)d_in[0];
  const int*   lengths = (const int*)d_in[1];
  const float* pos_emb = (const float*)d_in[2];
  const float* tok_emb = (const float*)d_in[3];
  const float* ln_emb_g = (const float*)d_in[4];
  const float* ln_emb_b = (const float*)d_in[5];
  const float* Wq = (const float*)d_in[6];
  const float* bq = (const float*)d_in[7];
  const float* Wk = (const float*)d_in[8];
  const float* bk = (const float*)d_in[9];
  const float* Wv = (const float*)d_in[10];
  const float* bv = (const float*)d_in[11];
  const float* Wo = (const float*)d_in[12];
  const float* bo = (const float*)d_in[13];
  const float* ln1_g = (const float*)d_in[14];
  const float* ln1_b = (const float*)d_in[15];
  const float* Wi = (const float*)d_in[16];
  const float* bi = (const float*)d_in[17];
  const float* Wf = (const float*)d_in[18];
  const float* bf2 = (const float*)d_in[19];
  const float* ln2_g = (const float*)d_in[20];
  const float* ln2_b = (const float*)d_in[21];

  const size_t MTOK = (size_t)2 * S_LEN;     // 8192
  const size_t DD  = (size_t)D_MODEL * D_MODEL;
  const size_t DDF = (size_t)D_MODEL * DFF_;

  char* ws = (char*)d_ws;
  size_t off = 0;
  auto alloc = [&](size_t bytes) { void* p = ws + off; off += (bytes + 255) & ~(size_t)255; return p; };

  short* xb    = (short*)alloc(MTOK * D_MODEL * 2);
  short* qkv   = (short*)alloc(MTOK * QKVN * 2);
  short* vtb   = (short*)alloc(MTOK * D_MODEL * 2);
  float* y     = (float*)alloc(MTOK * D_MODEL * 4);
  short* ctxb  = (short*)alloc(MTOK * D_MODEL * 2);
  short* hb    = (short*)alloc(MTOK * DFF_ * 2);
  short* wqkvt = (short*)alloc((size_t)NL * QKVN * D_MODEL * 2);
  short* wot   = (short*)alloc((size_t)NL * DD * 2);
  short* wit   = (short*)alloc((size_t)NL * DDF * 2);
  short* wft   = (short*)alloc((size_t)NL * DDF * 2);
  float* bqkv  = (float*)alloc((size_t)NL * QKVN * 4);
  float* x = (float*)d_out;

  const dim3 tb(32, 8);
  const size_t QL = (size_t)QKVN * D_MODEL;
  transpose_w<<<dim3(24, 24, NL), tb, 0, stream>>>(Wq, wqkvt,            D_MODEL, D_MODEL, DD, QL, 0.125f);
  transpose_w<<<dim3(24, 24, NL), tb, 0, stream>>>(Wk, wqkvt + 768*768,  D_MODEL, D_MODEL, DD, QL, 1.0f);
  transpose_w<<<dim3(24, 24, NL), tb, 0, stream>>>(Wv, wqkvt + 1536*768, D_MODEL, D_MODEL, DD, QL, 1.0f);
  transpose_w<<<dim3(24, 24, NL), tb, 0, stream>>>(Wo, wot, D_MODEL, D_MODEL, DD, DD, 1.0f);
  transpose_w<<<dim3(96, 24, NL), tb, 0, stream>>>(Wi, wit, D_MODEL, DFF_, DDF, DDF, 1.0f);
  transpose_w<<<dim3(24, 96, NL), tb, 0, stream>>>(Wf, wft, DFF_, D_MODEL, DDF, DDF, 1.0f);
  prep_bias<<<dim3(NL, 3), 768, 0, stream>>>(bq, bk, bv, bqkv);

  ln_kernel<0><<<MTOK, 256, 0, stream>>>(inputs, pos_emb, tok_emb, ln_emb_g, ln_emb_b, x, xb);

  for (int l = 0; l < NL; ++l) {
    gemm8p<4, 0><<<dim3(9, 32), 512, 0, stream>>>(xb, wqkvt + (size_t)l * QL, bqkv + (size_t)l * QKVN,
                                                  qkv, (int)MTOK, QKVN, D_MODEL);
    vtrans<<<dim3(64, NHEAD, 2), dim3(64, 8), 0, stream>>>(qkv, vtb);
    att_fused<<<dim3(1536), 256, 0, stream>>>(qkv, vtb, lengths, ctxb);
    gemm8p<2, 1><<<dim3(6, 32), 512, 0, stream>>>(ctxb, wot + (size_t)l * DD, bo + l * D_MODEL,
                                                  y, (int)MTOK, D_MODEL, D_MODEL);
    ln_kernel<1><<<MTOK, 256, 0, stream>>>(x, y, nullptr, ln1_g + l * D_MODEL, ln1_b + l * D_MODEL, x, xb);
    gemm8p<4, 2><<<dim3(12, 32), 512, 0, stream>>>(xb, wit + (size_t)l * DDF, bi + l * DFF_,
                                                   hb, (int)MTOK, DFF_, D_MODEL);
    gemm8p<2, 1><<<dim3(6, 32), 512, 0, stream>>>(hb, wft + (size_t)l * DDF, bf2 + l * D_MODEL,
                                                  y, (int)MTOK, D_MODEL, DFF_);
    ln_kernel<1><<<MTOK, 256, 0, stream>>>(x, y, nullptr, ln2_g + l * D_MODEL, ln2_b + l * D_MODEL, x, xb);
  }
}

// Round 6
// 1069.031 us; speedup vs baseline: 1.5662x; 1.2140x over previous
//
#include <hip/hip_runtime.h>
#include <cstdint>

#define S_LEN 4096
#define D_MODEL 768
#define NHEAD 12
#define DHE 64
#define DFF_ 3072
#define NL 4
#define W1_ 128
#define NC_ 32
#define QKVN 2304

typedef __attribute__((ext_vector_type(8))) short v8s;
typedef __attribute__((ext_vector_type(4))) float v4f;

__device__ __forceinline__ short f2bf(float f) {
  union { float f; unsigned u; } x; x.f = f;
  unsigned r = x.u + 0x7fffu + ((x.u >> 16) & 1u);
  return (short)(r >> 16);
}

__device__ __forceinline__ float b2f(short s) {
  union { unsigned u; float f; } x; x.u = ((unsigned)(unsigned short)s) << 16;
  return x.f;
}

__device__ __forceinline__ void load_lds16(const short* g, short* l) {
  __builtin_amdgcn_global_load_lds((const __attribute__((address_space(1))) void*)g,
                                   (__attribute__((address_space(3))) void*)l, 16, 0, 0);
}

// ---------------- 128x128 GEMM, 2 blocks/CU: C = A[M,K] @ Bt[N,K]^T + bias ----------------
// 4 waves (2x2), wave-tile 64x64. LDS 64KB (2 dbuf x (A+B) 16KB planes).
// T2 swizzle on 128B rows: byte ^= (row&7)<<4  (2-way on ds_read = free, verified layout).
// Pipeline: distance-2 prefetch, counted vmcnt(8), 2 barriers/K-tile.
// EPI 0: bf16 out (+bias). EPI 2: gelu -> bf16 (+bias).
template<int EPI>
__global__ __launch_bounds__(256, 2)
void gemm128(const short* __restrict__ A, const short* __restrict__ Bt,
             const float* __restrict__ bias, void* __restrict__ outp,
             int M, int N, int K)
{
  __shared__ short sA[2][128 * 64];
  __shared__ short sB[2][128 * 64];
  const int tid = threadIdx.x;
  const int lane = tid & 63, wid = tid >> 6;
  const int g = lane >> 4, l16 = lane & 15;
  const int wr = wid >> 1, wc = wid & 1;
  const int nt = K >> 6;

  // XCD-bijective swizzle (all grids have nwg % 8 == 0); bn-fastest within XCD chunk.
  const int gx = gridDim.x;
  const int nwg = gx * gridDim.y;
  const int p = blockIdx.y * gx + blockIdx.x;
  const int q8 = nwg >> 3;
  const int lb = (p & 7) * q8 + (p >> 3);
  const int bn_ = lb % gx, bm_ = lb / gx;

  const short* Ab = A + (size_t)(bm_ * 128) * K;
  const short* Bb = Bt + (size_t)(bn_ * 128) * K;

  // stage one K-tile (A and B planes, 8 gload_lds issues per thread total)
  auto stage = [&](int t, int bufi) {
#pragma unroll
    for (int i = 0; i < 4; ++i) {
      const int byte = i * 4096 + tid * 16;
      const int row = byte >> 7;
      const int lir = (byte & 127) ^ ((row & 7) << 4);
      const int wbase = (i * 4096 + wid * 1024) >> 1;
      load_lds16(Ab + (size_t)row * K + t * 64 + (lir >> 1), &sA[bufi][wbase]);
    }
#pragma unroll
    for (int i = 0; i < 4; ++i) {
      const int byte = i * 4096 + tid * 16;
      const int row = byte >> 7;
      const int lir = (byte & 127) ^ ((row & 7) << 4);
      const int wbase = (i * 4096 + wid * 1024) >> 1;
      load_lds16(Bb + (size_t)row * K + t * 64 + (lir >> 1), &sB[bufi][wbase]);
    }
  };

  auto ldf = [&](const short* plane, int row, int kk) -> v8s {
    const int b = (kk * 64 + g * 16) ^ ((row & 7) << 4);
    return *(const v8s*)((const char*)plane + row * 128 + b);
  };

  v4f acc[4][4] = {};

  stage(0, 0);
  stage(1, 1);
  asm volatile("s_waitcnt vmcnt(8)" ::: "memory");   // t0 complete, t1 in flight
  __builtin_amdgcn_s_barrier();

  for (int t = 0; t < nt; ++t) {
    const int cur = t & 1;
    const short* pA = sA[cur];
    const short* pB = sB[cur];
    v8s fa[2][4], fb[2][4];
#pragma unroll
    for (int kk = 0; kk < 2; ++kk) {
#pragma unroll
      for (int m = 0; m < 4; ++m) fa[kk][m] = ldf(pA, wr * 64 + m * 16 + l16, kk);
#pragma unroll
      for (int n = 0; n < 4; ++n) fb[kk][n] = ldf(pB, wc * 64 + n * 16 + l16, kk);
    }
    asm volatile("s_waitcnt lgkmcnt(0)" ::: "memory");
    __builtin_amdgcn_sched_barrier(0);
    __builtin_amdgcn_s_barrier();                    // all waves done reading buf[cur]
    if (t + 2 < nt) stage(t + 2, cur);               // overwrite freed buffer
    __builtin_amdgcn_sched_barrier(0);
    __builtin_amdgcn_s_setprio(1);
#pragma unroll
    for (int kk = 0; kk < 2; ++kk)
#pragma unroll
      for (int m = 0; m < 4; ++m)
#pragma unroll
        for (int n = 0; n < 4; ++n)
          acc[m][n] = __builtin_amdgcn_mfma_f32_16x16x32_bf16(fa[kk][m], fb[kk][n], acc[m][n], 0, 0, 0);
    __builtin_amdgcn_s_setprio(0);
    __builtin_amdgcn_sched_barrier(0);
    if (t + 2 < nt)      asm volatile("s_waitcnt vmcnt(8)" ::: "memory");  // t+1 done
    else if (t + 1 < nt) asm volatile("s_waitcnt vmcnt(0)" ::: "memory");  // drain last
    if (t + 1 < nt) __builtin_amdgcn_s_barrier();
  }

  // epilogue
  const int row0 = bm_ * 128 + wr * 64;
  const int col0 = bn_ * 128 + wc * 64;
#pragma unroll
  for (int m = 0; m < 4; ++m)
#pragma unroll
    for (int n = 0; n < 4; ++n) {
      const int col = col0 + n * 16 + l16;
      const float bc = bias[col];
#pragma unroll
      for (int r = 0; r < 4; ++r) {
        const int row = row0 + m * 16 + g * 4 + r;
        const float v = acc[m][n][r] + bc;
        if (EPI == 0) {
          ((short*)outp)[(size_t)row * N + col] = f2bf(v);
        } else {
          const float e = __expf(1.5957691216057308f * (v + 0.044715f * v * v * v));
          ((short*)outp)[(size_t)row * N + col] = f2bf(v - v / (1.0f + e));
        }
      }
    }
}

// ---------------- weight transpose f32[K,N] -> bf16[N,K] (with scale fold) ----------------
__global__ __launch_bounds__(256)
void transpose_w(const float* __restrict__ in, short* __restrict__ out, int K, int N,
                 size_t in_ls, size_t out_ls, float scale)
{
  __shared__ float t[32][33];
  const int n0 = blockIdx.x * 32, k0 = blockIdx.y * 32;
  const float* src = in + (size_t)blockIdx.z * in_ls;
  short* dst = out + (size_t)blockIdx.z * out_ls;
  const int tx = threadIdx.x, ty = threadIdx.y;   // (32,8)
#pragma unroll
  for (int i = 0; i < 4; ++i)
    t[ty + 8*i][tx] = src[(size_t)(k0 + ty + 8*i) * N + n0 + tx];
  __syncthreads();
#pragma unroll
  for (int i = 0; i < 4; ++i)
    dst[(size_t)(n0 + ty + 8*i) * K + k0 + tx] = f2bf(t[tx][ty + 8*i] * scale);
}

__global__ void prep_bias(const float* __restrict__ bq, const float* __restrict__ bk,
                          const float* __restrict__ bv, float* __restrict__ out)
{
  const int l = blockIdx.x, p = blockIdx.y, c = threadIdx.x;
  const float* s = p == 0 ? bq : (p == 1 ? bk : bv);
  out[(l * 3 + p) * 768 + c] = s[l * 768 + c] * (p == 0 ? 0.125f : 1.0f);
}

// ---------------- V transpose: qkv[B,S,2304] v-part -> vt [B,H,DH,S] ----------------
__global__ __launch_bounds__(512)
void vtrans(const short* __restrict__ qkv, short* __restrict__ vt)
{
  __shared__ short t[64][65];
  const int s0 = blockIdx.x * 64, h = blockIdx.y, b = blockIdx.z;
  const int tx = threadIdx.x, ty = threadIdx.y;   // (64,8)
#pragma unroll
  for (int i = 0; i < 8; ++i)
    t[ty + 8*i][tx] = qkv[(size_t)(b * S_LEN + s0 + ty + 8*i) * QKVN + 1536 + h * DHE + tx];
  __syncthreads();
#pragma unroll
  for (int i = 0; i < 8; ++i)
    vt[((size_t)(b * NHEAD + h) * DHE + ty + 8*i) * S_LEN + s0 + tx] = t[tx][ty + 8*i];
}

// ---------------- LayerNorm. MODE 0: embed (in0 + pos + tok), MODE 1: residual x + y(bf16) ----
template<int MODE>
__global__ __launch_bounds__(256)
void ln_kernel(const float* __restrict__ in0, const void* __restrict__ in1,
               const float* __restrict__ in2,
               const float* __restrict__ gamma, const float* __restrict__ beta,
               float* __restrict__ outf, short* __restrict__ outb)
{
  __shared__ float red[8];
  const int row = blockIdx.x;
  const int tid = threadIdx.x;
  const int wave = tid >> 6, lane = tid & 63;
  float v[3];
#pragma unroll
  for (int i = 0; i < 3; ++i) {
    const int c = tid + i * 256;
    const size_t idx = (size_t)row * D_MODEL + c;
    if (MODE == 0) {
      const int s = row & (S_LEN - 1);
      v[i] = in0[idx] + ((const float*)in1)[(size_t)(2 + s) * D_MODEL + c] + in2[c];
    } else {
      v[i] = in0[idx] + b2f(((const short*)in1)[idx]);
    }
  }
  float sum = v[0] + v[1] + v[2];
#pragma unroll
  for (int m = 1; m < 64; m <<= 1) sum += __shfl_xor(sum, m, 64);
  if (lane == 0) red[wave] = sum;
  __syncthreads();
  const float mean = (red[0] + red[1] + red[2] + red[3]) * (1.0f / 768.0f);
  float sq = 0.f;
#pragma unroll
  for (int i = 0; i < 3; ++i) { float d = v[i] - mean; sq += d * d; }
#pragma unroll
  for (int m = 1; m < 64; m <<= 1) sq += __shfl_xor(sq, m, 64);
  if (lane == 0) red[4 + wave] = sq;
  __syncthreads();
  const float var = (red[4] + red[5] + red[6] + red[7]) * (1.0f / 768.0f);
  const float rstd = 1.0f / sqrtf(var + 1e-12f);
#pragma unroll
  for (int i = 0; i < 3; ++i) {
    const int c = tid + i * 256;
    const size_t idx = (size_t)row * D_MODEL + c;
    const float o = (v[i] - mean) * rstd * gamma[c] + beta[c];
    outf[idx] = o;
    outb[idx] = f2bf(o);
  }
}

// ---------------- fused attention v3: batched-pipelined gathers, wave-private P ----------------
__global__ __launch_bounds__(256, 2)
void att_fused(const short* __restrict__ qkv, const short* __restrict__ vt,
               const int* __restrict__ lengths, short* __restrict__ ctx)
{
  __shared__ __align__(16) short Pl[4 * 16 * 392];
  const int p = blockIdx.x;
  const int lb = (p & 7) * 192 + (p >> 3);
  const int hq = lb & 1, c = (lb >> 1) & 31, bh = lb >> 6;
  const int b = bh / 12, h = bh - b * 12;
  const int len = lengths[b];
  const int wave = threadIdx.x >> 6, lane = threadIdx.x & 63;
  const int g = lane >> 4, l16 = lane & 15;
  const int qtile = hq * 64 + wave * 16;
  short* Pw = &Pl[wave * 16 * 392];

  const short* qp = qkv + (size_t)(b * S_LEN + c * W1_ + qtile + l16) * QKVN + h * DHE;
  const v8s a0 = *(const v8s*)(qp + g * 8);
  const v8s a1 = *(const v8s*)(qp + 32 + g * 8);

  const short* kbase = qkv + 768 + h * DHE;
  const short* vtb = vt + (size_t)(b * NHEAD + h) * DHE * S_LEN;
  const int j0 = c * W1_ - W1_;

  v4f s[24];
  v8s kf[2][4];
#pragma unroll
  for (int u = 0; u < 2; ++u) {
    const int jg = j0 + u * 16 + l16;
    const int jc = jg < 0 ? 0 : (jg > S_LEN - 1 ? S_LEN - 1 : jg);
    const short* kp = kbase + (size_t)(b * S_LEN + jc) * QKVN;
    kf[0][2 * u]     = *(const v8s*)(kp + g * 8);
    kf[0][2 * u + 1] = *(const v8s*)(kp + 32 + g * 8);
  }
#pragma unroll
  for (int i = 0; i < 12; ++i) {
    if (i < 11) {
#pragma unroll
      for (int u = 0; u < 2; ++u) {
        const int jg = j0 + (2 * (i + 1) + u) * 16 + l16;
        const int jc = jg < 0 ? 0 : (jg > S_LEN - 1 ? S_LEN - 1 : jg);
        const short* kp = kbase + (size_t)(b * S_LEN + jc) * QKVN;
        kf[(i + 1) & 1][2 * u]     = *(const v8s*)(kp + g * 8);
        kf[(i + 1) & 1][2 * u + 1] = *(const v8s*)(kp + 32 + g * 8);
      }
    }
    __builtin_amdgcn_sched_barrier(0);
    if (i < 11) asm volatile("s_waitcnt vmcnt(4)" ::: "memory");
    else        asm volatile("s_waitcnt vmcnt(0)" ::: "memory");
    __builtin_amdgcn_sched_barrier(0);
#pragma unroll
    for (int u = 0; u < 2; ++u) {
      v4f t = {0.f, 0.f, 0.f, 0.f};
      t = __builtin_amdgcn_mfma_f32_16x16x32_bf16(a0, kf[i & 1][2 * u], t, 0, 0, 0);
      t = __builtin_amdgcn_mfma_f32_16x16x32_bf16(a1, kf[i & 1][2 * u + 1], t, 0, 0, 0);
      s[2 * i + u] = t;
    }
  }

  v8s vf[2][4];
  {
    const int jg = j0 + g * 8;
    const int jc = jg < 0 ? 0 : (jg > S_LEN - 8 ? S_LEN - 8 : jg);
#pragma unroll
    for (int dt = 0; dt < 4; ++dt)
      vf[0][dt] = *(const v8s*)&vtb[(size_t)(dt * 16 + l16) * S_LEN + jc];
  }

#pragma unroll
  for (int r = 0; r < 4; ++r) {
    const int qpos = qtile + g * 4 + r;
    float m = -3.0e38f;
#pragma unroll
    for (int nt = 0; nt < 24; ++nt) {
      const int j = nt * 16 + l16;
      const int jg = j0 + j;
      const bool ok = (j >= qpos) & (j <= qpos + 2 * W1_) & (jg >= 0) & (jg < len);
      const float v = ok ? s[nt][r] : -1e9f;
      s[nt][r] = v;
      m = fmaxf(m, v);
    }
#pragma unroll
    for (int d = 1; d < 16; d <<= 1) m = fmaxf(m, __shfl_xor(m, d, 64));
    float su = 0.f;
#pragma unroll
    for (int nt = 0; nt < 24; ++nt) {
      const float e = __expf(s[nt][r] - m);
      s[nt][r] = e;
      su += e;
    }
#pragma unroll
    for (int d = 1; d < 16; d <<= 1) su += __shfl_xor(su, d, 64);
    const float f = (c * W1_ + qpos < len) ? 1.0f / su : 0.0f;
    short* prow = Pw + (g * 4 + r) * 392;
#pragma unroll
    for (int nt = 0; nt < 24; ++nt)
      prow[nt * 16 + l16] = f2bf(s[nt][r] * f);
  }
  asm volatile("s_waitcnt lgkmcnt(0)" ::: "memory");
  __builtin_amdgcn_sched_barrier(0);

  v4f acc[4] = {};
#pragma unroll
  for (int i = 0; i < 12; ++i) {
    if (i < 11) {
      const int jg = j0 + (i + 1) * 32 + g * 8;
      const int jc = jg < 0 ? 0 : (jg > S_LEN - 8 ? S_LEN - 8 : jg);
#pragma unroll
      for (int dt = 0; dt < 4; ++dt)
        vf[(i + 1) & 1][dt] = *(const v8s*)&vtb[(size_t)(dt * 16 + l16) * S_LEN + jc];
    }
    __builtin_amdgcn_sched_barrier(0);
    if (i < 11) asm volatile("s_waitcnt vmcnt(4)" ::: "memory");
    else        asm volatile("s_waitcnt vmcnt(0)" ::: "memory");
    __builtin_amdgcn_sched_barrier(0);
    const v8s fa = *(const v8s*)&Pw[l16 * 392 + i * 32 + g * 8];
#pragma unroll
    for (int dt = 0; dt < 4; ++dt)
      acc[dt] = __builtin_amdgcn_mfma_f32_16x16x32_bf16(fa, vf[i & 1][dt], acc[dt], 0, 0, 0);
  }
#pragma unroll
  for (int dt = 0; dt < 4; ++dt)
#pragma unroll
    for (int r = 0; r < 4; ++r) {
      const int srow = c * W1_ + qtile + g * 4 + r;
      ctx[(size_t)(b * S_LEN + srow) * D_MODEL + h * DHE + dt * 16 + l16] = f2bf(acc[dt][r]);
    }
}

extern "C" void kernel_launch(void* const* d_in, const int* in_sizes, int n_in,
                              void* d_out, int out_size, void* d_ws, size_t ws_size,
                              hipStream_t stream) {
  (void)in_sizes; (void)n_in; (void)out_size; (void)ws_size;
  const float* inputs  = (const float*)d_in[0];
  const int*   lengths = (const int*)d_in[1];
  const float* pos_emb = (const float*)d_in[2];
  const float* tok_emb = (const float*)d_in[3];
  const float* ln_emb_g = (const float*)d_in[4];
  const float* ln_emb_b = (const float*)d_in[5];
  const float* Wq = (const float*)d_in[6];
  const float* bq = (const float*)d_in[7];
  const float* Wk = (const float*)d_in[8];
  const float* bk = (const float*)d_in[9];
  const float* Wv = (const float*)d_in[10];
  const float* bv = (const float*)d_in[11];
  const float* Wo = (const float*)d_in[12];
  const float* bo = (const float*)d_in[13];
  const float* ln1_g = (const float*)d_in[14];
  const float* ln1_b = (const float*)d_in[15];
  const float* Wi = (const float*)d_in[16];
  const float* bi = (const float*)d_in[17];
  const float* Wf = (const float*)d_in[18];
  const float* bf2 = (const float*)d_in[19];
  const float* ln2_g = (const float*)d_in[20];
  const float* ln2_b = (const float*)d_in[21];

  const size_t MTOK = (size_t)2 * S_LEN;     // 8192
  const size_t DD  = (size_t)D_MODEL * D_MODEL;
  const size_t DDF = (size_t)D_MODEL * DFF_;

  char* ws = (char*)d_ws;
  size_t off = 0;
  auto alloc = [&](size_t bytes) { void* p = ws + off; off += (bytes + 255) & ~(size_t)255; return p; };

  short* xb    = (short*)alloc(MTOK * D_MODEL * 2);
  short* qkv   = (short*)alloc(MTOK * QKVN * 2);
  short* vtb   = (short*)alloc(MTOK * D_MODEL * 2);
  short* yb    = (short*)alloc(MTOK * D_MODEL * 2);
  short* ctxb  = (short*)alloc(MTOK * D_MODEL * 2);
  short* hb    = (short*)alloc(MTOK * DFF_ * 2);
  short* wqkvt = (short*)alloc((size_t)NL * QKVN * D_MODEL * 2);
  short* wot   = (short*)alloc((size_t)NL * DD * 2);
  short* wit   = (short*)alloc((size_t)NL * DDF * 2);
  short* wft   = (short*)alloc((size_t)NL * DDF * 2);
  float* bqkv  = (float*)alloc((size_t)NL * QKVN * 4);
  float* x = (float*)d_out;

  const dim3 tb(32, 8);
  const size_t QL = (size_t)QKVN * D_MODEL;
  transpose_w<<<dim3(24, 24, NL), tb, 0, stream>>>(Wq, wqkvt,            D_MODEL, D_MODEL, DD, QL, 0.125f);
  transpose_w<<<dim3(24, 24, NL), tb, 0, stream>>>(Wk, wqkvt + 768*768,  D_MODEL, D_MODEL, DD, QL, 1.0f);
  transpose_w<<<dim3(24, 24, NL), tb, 0, stream>>>(Wv, wqkvt + 1536*768, D_MODEL, D_MODEL, DD, QL, 1.0f);
  transpose_w<<<dim3(24, 24, NL), tb, 0, stream>>>(Wo, wot, D_MODEL, D_MODEL, DD, DD, 1.0f);
  transpose_w<<<dim3(96, 24, NL), tb, 0, stream>>>(Wi, wit, D_MODEL, DFF_, DDF, DDF, 1.0f);
  transpose_w<<<dim3(24, 96, NL), tb, 0, stream>>>(Wf, wft, DFF_, D_MODEL, DDF, DDF, 1.0f);
  prep_bias<<<dim3(NL, 3), 768, 0, stream>>>(bq, bk, bv, bqkv);

  ln_kernel<0><<<MTOK, 256, 0, stream>>>(inputs, pos_emb, tok_emb, ln_emb_g, ln_emb_b, x, xb);

  for (int l = 0; l < NL; ++l) {
    gemm128<0><<<dim3(18, 64), 256, 0, stream>>>(xb, wqkvt + (size_t)l * QL, bqkv + (size_t)l * QKVN,
                                                 qkv, (int)MTOK, QKVN, D_MODEL);
    vtrans<<<dim3(64, NHEAD, 2), dim3(64, 8), 0, stream>>>(qkv, vtb);
    att_fused<<<dim3(1536), 256, 0, stream>>>(qkv, vtb, lengths, ctxb);
    gemm128<0><<<dim3(6, 64), 256, 0, stream>>>(ctxb, wot + (size_t)l * DD, bo + l * D_MODEL,
                                                yb, (int)MTOK, D_MODEL, D_MODEL);
    ln_kernel<1><<<MTOK, 256, 0, stream>>>(x, yb, nullptr, ln1_g + l * D_MODEL, ln1_b + l * D_MODEL, x, xb);
    gemm128<2><<<dim3(24, 64), 256, 0, stream>>>(xb, wit + (size_t)l * DDF, bi + l * DFF_,
                                                 hb, (int)MTOK, DFF_, D_MODEL);
    gemm128<0><<<dim3(6, 64), 256, 0, stream>>>(hb, wft + (size_t)l * DDF, bf2 + l * D_MODEL,
                                                yb, (int)MTOK, D_MODEL, DFF_);
    ln_kernel<1><<<MTOK, 256, 0, stream>>>(x, yb, nullptr, ln2_g + l * D_MODEL, ln2_b + l * D_MODEL, x, xb);
  }
}

// Round 7
// 895.490 us; speedup vs baseline: 1.8697x; 1.1938x over previous
//
#include <hip/hip_runtime.h>
#include <cstdint>

#define S_LEN 4096
#define D_MODEL 768
#define NHEAD 12
#define DHE 64
#define DFF_ 3072
#define NL 4
#define W1_ 128
#define NC_ 32
#define QKVN 2304

typedef __attribute__((ext_vector_type(8))) short v8s;
typedef __attribute__((ext_vector_type(4))) short v4s;
typedef __attribute__((ext_vector_type(4))) float v4f;

__device__ __forceinline__ short f2bf(float f) {
  union { float f; unsigned u; } x; x.f = f;
  unsigned r = x.u + 0x7fffu + ((x.u >> 16) & 1u);
  return (short)(r >> 16);
}

__device__ __forceinline__ float b2f(short s) {
  union { unsigned u; float f; } x; x.u = ((unsigned)(unsigned short)s) << 16;
  return x.f;
}

__device__ __forceinline__ void load_lds16(const short* g, short* l) {
  __builtin_amdgcn_global_load_lds((const __attribute__((address_space(1))) void*)g,
                                   (__attribute__((address_space(3))) void*)l, 16, 0, 0);
}

// ---------------- 128x128 GEMM, 2 blocks/CU (unchanged from R6) ----------------
template<int EPI>
__global__ __launch_bounds__(256, 2)
void gemm128(const short* __restrict__ A, const short* __restrict__ Bt,
             const float* __restrict__ bias, void* __restrict__ outp,
             int M, int N, int K)
{
  __shared__ short sA[2][128 * 64];
  __shared__ short sB[2][128 * 64];
  const int tid = threadIdx.x;
  const int lane = tid & 63, wid = tid >> 6;
  const int g = lane >> 4, l16 = lane & 15;
  const int wr = wid >> 1, wc = wid & 1;
  const int nt = K >> 6;

  const int gx = gridDim.x;
  const int nwg = gx * gridDim.y;
  const int p = blockIdx.y * gx + blockIdx.x;
  const int q8 = nwg >> 3;
  const int lb = (p & 7) * q8 + (p >> 3);
  const int bn_ = lb % gx, bm_ = lb / gx;

  const short* Ab = A + (size_t)(bm_ * 128) * K;
  const short* Bb = Bt + (size_t)(bn_ * 128) * K;

  auto stage = [&](int t, int bufi) {
#pragma unroll
    for (int i = 0; i < 4; ++i) {
      const int byte = i * 4096 + tid * 16;
      const int row = byte >> 7;
      const int lir = (byte & 127) ^ ((row & 7) << 4);
      const int wbase = (i * 4096 + wid * 1024) >> 1;
      load_lds16(Ab + (size_t)row * K + t * 64 + (lir >> 1), &sA[bufi][wbase]);
    }
#pragma unroll
    for (int i = 0; i < 4; ++i) {
      const int byte = i * 4096 + tid * 16;
      const int row = byte >> 7;
      const int lir = (byte & 127) ^ ((row & 7) << 4);
      const int wbase = (i * 4096 + wid * 1024) >> 1;
      load_lds16(Bb + (size_t)row * K + t * 64 + (lir >> 1), &sB[bufi][wbase]);
    }
  };

  auto ldf = [&](const short* plane, int row, int kk) -> v8s {
    const int b = (kk * 64 + g * 16) ^ ((row & 7) << 4);
    return *(const v8s*)((const char*)plane + row * 128 + b);
  };

  v4f acc[4][4] = {};

  stage(0, 0);
  stage(1, 1);
  asm volatile("s_waitcnt vmcnt(8)" ::: "memory");
  __builtin_amdgcn_s_barrier();

  for (int t = 0; t < nt; ++t) {
    const int cur = t & 1;
    const short* pA = sA[cur];
    const short* pB = sB[cur];
    v8s fa[2][4], fb[2][4];
#pragma unroll
    for (int kk = 0; kk < 2; ++kk) {
#pragma unroll
      for (int m = 0; m < 4; ++m) fa[kk][m] = ldf(pA, wr * 64 + m * 16 + l16, kk);
#pragma unroll
      for (int n = 0; n < 4; ++n) fb[kk][n] = ldf(pB, wc * 64 + n * 16 + l16, kk);
    }
    asm volatile("s_waitcnt lgkmcnt(0)" ::: "memory");
    __builtin_amdgcn_sched_barrier(0);
    __builtin_amdgcn_s_barrier();
    if (t + 2 < nt) stage(t + 2, cur);
    __builtin_amdgcn_sched_barrier(0);
    __builtin_amdgcn_s_setprio(1);
#pragma unroll
    for (int kk = 0; kk < 2; ++kk)
#pragma unroll
      for (int m = 0; m < 4; ++m)
#pragma unroll
        for (int n = 0; n < 4; ++n)
          acc[m][n] = __builtin_amdgcn_mfma_f32_16x16x32_bf16(fa[kk][m], fb[kk][n], acc[m][n], 0, 0, 0);
    __builtin_amdgcn_s_setprio(0);
    __builtin_amdgcn_sched_barrier(0);
    if (t + 2 < nt)      asm volatile("s_waitcnt vmcnt(8)" ::: "memory");
    else if (t + 1 < nt) asm volatile("s_waitcnt vmcnt(0)" ::: "memory");
    if (t + 1 < nt) __builtin_amdgcn_s_barrier();
  }

  const int row0 = bm_ * 128 + wr * 64;
  const int col0 = bn_ * 128 + wc * 64;
#pragma unroll
  for (int m = 0; m < 4; ++m)
#pragma unroll
    for (int n = 0; n < 4; ++n) {
      const int col = col0 + n * 16 + l16;
      const float bc = bias[col];
#pragma unroll
      for (int r = 0; r < 4; ++r) {
        const int row = row0 + m * 16 + g * 4 + r;
        const float v = acc[m][n][r] + bc;
        if (EPI == 0) {
          ((short*)outp)[(size_t)row * N + col] = f2bf(v);
        } else {
          const float e = __expf(1.5957691216057308f * (v + 0.044715f * v * v * v));
          ((short*)outp)[(size_t)row * N + col] = f2bf(v - v / (1.0f + e));
        }
      }
    }
}

// ---------------- weight transpose f32[K,N] -> bf16[N,K] (with scale fold) ----------------
__global__ __launch_bounds__(256)
void transpose_w(const float* __restrict__ in, short* __restrict__ out, int K, int N,
                 size_t in_ls, size_t out_ls, float scale)
{
  __shared__ float t[32][33];
  const int n0 = blockIdx.x * 32, k0 = blockIdx.y * 32;
  const float* src = in + (size_t)blockIdx.z * in_ls;
  short* dst = out + (size_t)blockIdx.z * out_ls;
  const int tx = threadIdx.x, ty = threadIdx.y;   // (32,8)
#pragma unroll
  for (int i = 0; i < 4; ++i)
    t[ty + 8*i][tx] = src[(size_t)(k0 + ty + 8*i) * N + n0 + tx];
  __syncthreads();
#pragma unroll
  for (int i = 0; i < 4; ++i)
    dst[(size_t)(n0 + ty + 8*i) * K + k0 + tx] = f2bf(t[tx][ty + 8*i] * scale);
}

__global__ void prep_bias(const float* __restrict__ bq, const float* __restrict__ bk,
                          const float* __restrict__ bv, float* __restrict__ out)
{
  const int l = blockIdx.x, p = blockIdx.y, c = threadIdx.x;
  const float* s = p == 0 ? bq : (p == 1 ? bk : bv);
  out[(l * 3 + p) * 768 + c] = s[l * 768 + c] * (p == 0 ? 0.125f : 1.0f);
}

// ---------------- V transpose: qkv[B,S,2304] v-part -> vt [B,H,DH,S] ----------------
__global__ __launch_bounds__(512)
void vtrans(const short* __restrict__ qkv, short* __restrict__ vt)
{
  __shared__ short t[64][65];
  const int s0 = blockIdx.x * 64, h = blockIdx.y, b = blockIdx.z;
  const int tx = threadIdx.x, ty = threadIdx.y;   // (64,8)
#pragma unroll
  for (int i = 0; i < 8; ++i)
    t[ty + 8*i][tx] = qkv[(size_t)(b * S_LEN + s0 + ty + 8*i) * QKVN + 1536 + h * DHE + tx];
  __syncthreads();
#pragma unroll
  for (int i = 0; i < 8; ++i)
    vt[((size_t)(b * NHEAD + h) * DHE + ty + 8*i) * S_LEN + s0 + tx] = t[tx][ty + 8*i];
}

// ---------------- LayerNorm. MODE 0: embed, MODE 1: residual x + y(bf16) ----------------
template<int MODE>
__global__ __launch_bounds__(256)
void ln_kernel(const float* __restrict__ in0, const void* __restrict__ in1,
               const float* __restrict__ in2,
               const float* __restrict__ gamma, const float* __restrict__ beta,
               float* __restrict__ outf, short* __restrict__ outb)
{
  __shared__ float red[8];
  const int row = blockIdx.x;
  const int tid = threadIdx.x;
  const int wave = tid >> 6, lane = tid & 63;
  float v[3];
#pragma unroll
  for (int i = 0; i < 3; ++i) {
    const int c = tid + i * 256;
    const size_t idx = (size_t)row * D_MODEL + c;
    if (MODE == 0) {
      const int s = row & (S_LEN - 1);
      v[i] = in0[idx] + ((const float*)in1)[(size_t)(2 + s) * D_MODEL + c] + in2[c];
    } else {
      v[i] = in0[idx] + b2f(((const short*)in1)[idx]);
    }
  }
  float sum = v[0] + v[1] + v[2];
#pragma unroll
  for (int m = 1; m < 64; m <<= 1) sum += __shfl_xor(sum, m, 64);
  if (lane == 0) red[wave] = sum;
  __syncthreads();
  const float mean = (red[0] + red[1] + red[2] + red[3]) * (1.0f / 768.0f);
  float sq = 0.f;
#pragma unroll
  for (int i = 0; i < 3; ++i) { float d = v[i] - mean; sq += d * d; }
#pragma unroll
  for (int m = 1; m < 64; m <<= 1) sq += __shfl_xor(sq, m, 64);
  if (lane == 0) red[4 + wave] = sq;
  __syncthreads();
  const float var = (red[4] + red[5] + red[6] + red[7]) * (1.0f / 768.0f);
  const float rstd = 1.0f / sqrtf(var + 1e-12f);
#pragma unroll
  for (int i = 0; i < 3; ++i) {
    const int c = tid + i * 256;
    const size_t idx = (size_t)row * D_MODEL + c;
    const float o = (v[i] - mean) * rstd * gamma[c] + beta[c];
    outf[idx] = o;
    outb[idx] = f2bf(o);
  }
}

// ---------------- fused attention v4: LDS-staged K/V, swapped QK^T, P over K ----------------
// grid 1536 = (b,h,c,hq), 256 thr (4 waves x 16 q-rows). LDS 80KB -> 2 blocks/CU.
// Stage K-window [320][128B] + Vt-window [64][640B] via global_load_lds (swizzled src,
// rule 21), one vmcnt(0)+barrier, then all compute from LDS. Swapped mfma(K,Q): lane
// owns q-row l16 -> P row lane-local; P [64][640B] overwrites consumed K region after
// a cross-wave barrier. All LDS rows XOR-swizzled ^((row&7)<<4) -> ~2-way conflicts.
__global__ __launch_bounds__(256, 2)
void att_fused(const short* __restrict__ qkv, const short* __restrict__ vt,
               const int* __restrict__ lengths, short* __restrict__ ctx)
{
  __shared__ __align__(16) short KP[320 * 64];   // K-window; later P [64][640B]
  __shared__ __align__(16) short Vl[64 * 320];   // Vt-window [64][640B]
  const int p = blockIdx.x;
  const int lb = (p & 7) * 192 + (p >> 3);       // XCD-contiguous: same (b,h) per XCD
  const int hq = lb & 1, c = (lb >> 1) & 31, bh = lb >> 6;
  const int b = bh / 12, h = bh - b * 12;
  const int len = lengths[b];
  const int tid = threadIdx.x;
  const int wave = tid >> 6, lane = tid & 63;
  const int g = lane >> 4, l16 = lane & 15;
  const int j0h = c * W1_ + hq * 64 - W1_;       // global j of window index 0

  // ---- stage K window (rows clamped; finite data, masked later)
  {
    const int row0 = tid >> 3;
    const int o = (tid & 7) * 16;
    const char* kcol = (const char*)qkv + (size_t)b * S_LEN * 4608 + 1536 + h * 128;
#pragma unroll
    for (int i = 0; i < 10; ++i) {
      const int r_ = i * 32 + row0;
      const int op = o ^ ((r_ & 7) << 4);
      int jg = j0h + r_;
      jg = jg < 0 ? 0 : (jg > S_LEN - 1 ? S_LEN - 1 : jg);
      load_lds16((const short*)(kcol + (size_t)jg * 4608 + op),
                 (short*)((char*)KP + i * 4096 + wave * 1024));
    }
  }
  // ---- stage Vt window (col bytes clamped)
  {
    const char* vrow = (const char*)vt + ((size_t)(b * NHEAD + h) * DHE) * (S_LEN * 2);
#pragma unroll
    for (int r = 0; r < 10; ++r) {
      const int off = r * 4096 + tid * 16;
      const int rw = (int)(((unsigned)off * 6554u) >> 22);   // off / 640
      const int o = off - rw * 640;
      int jb = j0h * 2 + (o ^ ((rw & 7) << 4));
      jb = jb < 0 ? 0 : (jb > S_LEN * 2 - 16 ? S_LEN * 2 - 16 : jb);
      load_lds16((const short*)(vrow + (size_t)rw * (S_LEN * 2) + jb),
                 (short*)((char*)Vl + r * 4096 + wave * 1024));
    }
  }
  // ---- Q fragments (drained together with staging)
  const int qrow = c * W1_ + hq * 64 + wave * 16 + l16;      // this lane's q (S index)
  const short* qp = qkv + (size_t)(b * S_LEN + qrow) * QKVN + h * DHE;
  const v8s a0 = *(const v8s*)(qp + g * 8);
  const v8s a1 = *(const v8s*)(qp + 32 + g * 8);

  asm volatile("s_waitcnt vmcnt(0)" ::: "memory");
  __builtin_amdgcn_sched_barrier(0);
  __builtin_amdgcn_s_barrier();

  // ---- swapped QK^T: s[nt][r] = S[q = qrow][k = j0h + nt*16 + g*4 + r]
  v4f s[20];
  const int kswz = (l16 & 7) << 4;
#pragma unroll
  for (int nt = 0; nt < 20; ++nt) {
    const char* krow = (const char*)KP + (nt * 16 + l16) * 128;
    const v8s k0 = *(const v8s*)(krow + ((g * 16) ^ kswz));
    const v8s k1 = *(const v8s*)(krow + ((64 + g * 16) ^ kswz));
    v4f t = {0.f, 0.f, 0.f, 0.f};
    t = __builtin_amdgcn_mfma_f32_16x16x32_bf16(k0, a0, t, 0, 0, 0);
    t = __builtin_amdgcn_mfma_f32_16x16x32_bf16(k1, a1, t, 0, 0, 0);
    s[nt] = t;
  }

  // ---- mask + softmax: lane owns row q; reduce across the 4 groups (xor 16, 32)
  const int qloc = wave * 16 + l16;               // q - (j0h + 128)
  float m = -3.0e38f;
#pragma unroll
  for (int nt = 0; nt < 20; ++nt)
#pragma unroll
    for (int r = 0; r < 4; ++r) {
      const int j = nt * 16 + g * 4 + r;
      const int jg = j0h + j;
      const bool ok = (j >= qloc) & (j <= qloc + 2 * W1_) & (jg >= 0) & (jg < len);
      const float v = ok ? s[nt][r] : -1e9f;
      s[nt][r] = v;
      m = fmaxf(m, v);
    }
  m = fmaxf(m, __shfl_xor(m, 16, 64));
  m = fmaxf(m, __shfl_xor(m, 32, 64));
  float su = 0.f;
#pragma unroll
  for (int nt = 0; nt < 20; ++nt)
#pragma unroll
    for (int r = 0; r < 4; ++r) {
      const float e = __expf(s[nt][r] - m);
      s[nt][r] = e;
      su += e;
    }
  su += __shfl_xor(su, 16, 64);
  su += __shfl_xor(su, 32, 64);
  const float f = (qrow < len) ? 1.0f / su : 0.0f;

  // ---- all waves done reading K-LDS -> overwrite with P [64][640B]
  __builtin_amdgcn_s_barrier();
  const int pswz = (qloc & 7) << 4;
  char* prow = (char*)KP + qloc * 640;
#pragma unroll
  for (int nt = 0; nt < 20; ++nt) {
    v4s pk;
#pragma unroll
    for (int r = 0; r < 4; ++r) pk[r] = f2bf(s[nt][r] * f);
    *(v4s*)(prow + ((nt * 32 + g * 8) ^ pswz)) = pk;
  }
  asm volatile("s_waitcnt lgkmcnt(0)" ::: "memory");  // own rows only -> no barrier
  __builtin_amdgcn_sched_barrier(0);

  // ---- PV from LDS: C[q = g*4+r][d = dt*16+l16]
  v4f acc[4] = {};
#pragma unroll
  for (int kc = 0; kc < 10; ++kc) {
    const v8s fa = *(const v8s*)(prow + ((kc * 64 + g * 16) ^ pswz));
#pragma unroll
    for (int dt = 0; dt < 4; ++dt) {
      const int vr = dt * 16 + l16;
      const v8s fb = *(const v8s*)((char*)Vl + vr * 640 + ((kc * 64 + g * 16) ^ ((vr & 7) << 4)));
      acc[dt] = __builtin_amdgcn_mfma_f32_16x16x32_bf16(fa, fb, acc[dt], 0, 0, 0);
    }
  }
  const int srow0 = c * W1_ + hq * 64 + wave * 16;
#pragma unroll
  for (int dt = 0; dt < 4; ++dt)
#pragma unroll
    for (int r = 0; r < 4; ++r)
      ctx[(size_t)(b * S_LEN + srow0 + g * 4 + r) * D_MODEL + h * DHE + dt * 16 + l16] = f2bf(acc[dt][r]);
}

extern "C" void kernel_launch(void* const* d_in, const int* in_sizes, int n_in,
                              void* d_out, int out_size, void* d_ws, size_t ws_size,
                              hipStream_t stream) {
  (void)in_sizes; (void)n_in; (void)out_size; (void)ws_size;
  const float* inputs  = (const float*)d_in[0];
  const int*   lengths = (const int*)d_in[1];
  const float* pos_emb = (const float*)d_in[2];
  const float* tok_emb = (const float*)d_in[3];
  const float* ln_emb_g = (const float*)d_in[4];
  const float* ln_emb_b = (const float*)d_in[5];
  const float* Wq = (const float*)d_in[6];
  const float* bq = (const float*)d_in[7];
  const float* Wk = (const float*)d_in[8];
  const float* bk = (const float*)d_in[9];
  const float* Wv = (const float*)d_in[10];
  const float* bv = (const float*)d_in[11];
  const float* Wo = (const float*)d_in[12];
  const float* bo = (const float*)d_in[13];
  const float* ln1_g = (const float*)d_in[14];
  const float* ln1_b = (const float*)d_in[15];
  const float* Wi = (const float*)d_in[16];
  const float* bi = (const float*)d_in[17];
  const float* Wf = (const float*)d_in[18];
  const float* bf2 = (const float*)d_in[19];
  const float* ln2_g = (const float*)d_in[20];
  const float* ln2_b = (const float*)d_in[21];

  const size_t MTOK = (size_t)2 * S_LEN;     // 8192
  const size_t DD  = (size_t)D_MODEL * D_MODEL;
  const size_t DDF = (size_t)D_MODEL * DFF_;

  char* ws = (char*)d_ws;
  size_t off = 0;
  auto alloc = [&](size_t bytes) { void* p = ws + off; off += (bytes + 255) & ~(size_t)255; return p; };

  short* xb    = (short*)alloc(MTOK * D_MODEL * 2);
  short* qkv   = (short*)alloc(MTOK * QKVN * 2);
  short* vtb   = (short*)alloc(MTOK * D_MODEL * 2);
  short* yb    = (short*)alloc(MTOK * D_MODEL * 2);
  short* ctxb  = (short*)alloc(MTOK * D_MODEL * 2);
  short* hb    = (short*)alloc(MTOK * DFF_ * 2);
  short* wqkvt = (short*)alloc((size_t)NL * QKVN * D_MODEL * 2);
  short* wot   = (short*)alloc((size_t)NL * DD * 2);
  short* wit   = (short*)alloc((size_t)NL * DDF * 2);
  short* wft   = (short*)alloc((size_t)NL * DDF * 2);
  float* bqkv  = (float*)alloc((size_t)NL * QKVN * 4);
  float* x = (float*)d_out;

  const dim3 tb(32, 8);
  const size_t QL = (size_t)QKVN * D_MODEL;
  transpose_w<<<dim3(24, 24, NL), tb, 0, stream>>>(Wq, wqkvt,            D_MODEL, D_MODEL, DD, QL, 0.125f);
  transpose_w<<<dim3(24, 24, NL), tb, 0, stream>>>(Wk, wqkvt + 768*768,  D_MODEL, D_MODEL, DD, QL, 1.0f);
  transpose_w<<<dim3(24, 24, NL), tb, 0, stream>>>(Wv, wqkvt + 1536*768, D_MODEL, D_MODEL, DD, QL, 1.0f);
  transpose_w<<<dim3(24, 24, NL), tb, 0, stream>>>(Wo, wot, D_MODEL, D_MODEL, DD, DD, 1.0f);
  transpose_w<<<dim3(96, 24, NL), tb, 0, stream>>>(Wi, wit, D_MODEL, DFF_, DDF, DDF, 1.0f);
  transpose_w<<<dim3(24, 96, NL), tb, 0, stream>>>(Wf, wft, DFF_, D_MODEL, DDF, DDF, 1.0f);
  prep_bias<<<dim3(NL, 3), 768, 0, stream>>>(bq, bk, bv, bqkv);

  ln_kernel<0><<<MTOK, 256, 0, stream>>>(inputs, pos_emb, tok_emb, ln_emb_g, ln_emb_b, x, xb);

  for (int l = 0; l < NL; ++l) {
    gemm128<0><<<dim3(18, 64), 256, 0, stream>>>(xb, wqkvt + (size_t)l * QL, bqkv + (size_t)l * QKVN,
                                                 qkv, (int)MTOK, QKVN, D_MODEL);
    vtrans<<<dim3(64, NHEAD, 2), dim3(64, 8), 0, stream>>>(qkv, vtb);
    att_fused<<<dim3(1536), 256, 0, stream>>>(qkv, vtb, lengths, ctxb);
    gemm128<0><<<dim3(6, 64), 256, 0, stream>>>(ctxb, wot + (size_t)l * DD, bo + l * D_MODEL,
                                                yb, (int)MTOK, D_MODEL, D_MODEL);
    ln_kernel<1><<<MTOK, 256, 0, stream>>>(x, yb, nullptr, ln1_g + l * D_MODEL, ln1_b + l * D_MODEL, x, xb);
    gemm128<2><<<dim3(24, 64), 256, 0, stream>>>(xb, wit + (size_t)l * DDF, bi + l * DFF_,
                                                 hb, (int)MTOK, DFF_, D_MODEL);
    gemm128<0><<<dim3(6, 64), 256, 0, stream>>>(hb, wft + (size_t)l * DDF, bf2 + l * D_MODEL,
                                                yb, (int)MTOK, D_MODEL, DFF_);
    ln_kernel<1><<<MTOK, 256, 0, stream>>>(x, yb, nullptr, ln2_g + l * D_MODEL, ln2_b + l * D_MODEL, x, xb);
  }
}